// Round 5
// baseline (912.139 us; speedup 1.0000x reference)
//
#include <hip/hip_runtime.h>
#include <math.h>

#define BB 512
#define SS 128
#define EE 300
#define HH 300
#define FCIN 1800
#define LLI 2
#define KP 320          // padded K / leading dim for fp16 tensors

using half8 = __attribute__((ext_vector_type(8))) _Float16;
using h2    = __attribute__((ext_vector_type(2))) _Float16;
using f32x4 = __attribute__((ext_vector_type(4))) float;

__device__ __forceinline__ float fast_tanh(float x){
    float ax = fabsf(x);
    float t = __expf(-2.f*ax);
    float r = (1.f - t) / (1.f + t);
    return copysignf(r, x);
}

// norm accumulate of a half8 via 4 fdot2 (constant-index pair extraction)
__device__ __forceinline__ float norm8(half8 hv, float n){
    h2 p0 = __builtin_shufflevector(hv, hv, 0, 1);
    h2 p1 = __builtin_shufflevector(hv, hv, 2, 3);
    h2 p2 = __builtin_shufflevector(hv, hv, 4, 5);
    h2 p3 = __builtin_shufflevector(hv, hv, 6, 7);
    n = __builtin_amdgcn_fdot2(p0, p0, n, false);
    n = __builtin_amdgcn_fdot2(p1, p1, n, false);
    n = __builtin_amdgcn_fdot2(p2, p2, n, false);
    n = __builtin_amdgcn_fdot2(p3, p3, n, false);
    return n;
}

// ftile swizzle: [128][320] halves (640B row = 5x128B); XOR the 16B-chunk index
// with row&7 inside each 128B group -> conflict-free strided row access.
__device__ __forceinline__ int fswz(int row, int col){
    int ch = col >> 3;
    int chs = (ch & ~7) | ((ch ^ row) & 7);
    return row*320 + chs*8 + (col & 7);
}

// ---------------- Wt build: Wt[it][e][j] = W[it][j][e], fp16, e zero-padded to 320
__global__ void wt_build_kernel(const float* __restrict__ W, _Float16* __restrict__ Wt){
    int idx = blockIdx.x*256 + threadIdx.x;      // 2*320*128 = 81920
    if (idx >= 2*KP*SS) return;
    int j = idx & 127;
    int e = (idx >> 7) % KP;
    int it = idx / (KP*SS);
    float v = (e < EE) ? W[(size_t)it*SS*EE + j*EE + e] : 0.f;
    Wt[idx] = (_Float16)v;
}

// ---------------- pack conv weights: per it, 32 dwords:
// [0..5] h2(w0,w1) per (c,dy); [6..11] h2(w1,w2); [12..17] f32 w0; [18..23] f32 w2; [24] bias
__global__ void cwpack_kernel(const float* __restrict__ cw, const float* __restrict__ cb,
                              float* __restrict__ pwt){
    int t = threadIdx.x;
    if (t < 12){
        int it = t / 6, rem = t % 6;          // rem = c*3+dy
        const float* w = cw + it*18 + rem*3;
        float a = w[0], b = w[1], d = w[2];
        h2 p01 = { (_Float16)a, (_Float16)b };
        h2 p12 = { (_Float16)b, (_Float16)d };
        float* o = pwt + it*32;
        ((unsigned*)o)[rem]   = __builtin_bit_cast(unsigned, p01);
        ((unsigned*)o)[6+rem] = __builtin_bit_cast(unsigned, p12);
        o[12+rem] = a;
        o[18+rem] = d;
    }
    if (t < 2) pwt[t*32+24] = cb[t];
}

// ---------------- embed: gather -> sf16 + valid mask + fused seg-0 mean ------
// grid (bc, 32, 2), block 256 (4 waves, wave = 1 row); res must be zeroed
__global__ __launch_bounds__(256) void embed_kernel(
    const int* __restrict__ seq1, const int* __restrict__ seq2,
    const float* __restrict__ emb,
    _Float16* __restrict__ sf1, _Float16* __restrict__ sf2,
    float* __restrict__ v1, float* __restrict__ v2,
    float* __restrict__ res, int b0){
    __shared__ float mred[4][320];
    int bl = blockIdx.x, which = blockIdx.z;
    int w = threadIdx.x >> 6;
    int r = blockIdx.y*4 + w;
    int l = threadIdx.x & 63;
    const int* seq = which ? seq2 : seq1;
    _Float16* sfg = (which ? sf2 : sf1) + (size_t)bl*SS*KP;
    float* vd = (which ? v2 : v1) + bl*SS;
    int token = seq[(size_t)(b0+bl)*SS + r];
    if (l == 0) vd[r] = (token != 0) ? 1.f : 0.f;
    const float* er = emb + (size_t)token * EE;
    int e0 = l*8;
    float x[8];
    if (l < 37){
        float4 a = *(const float4*)(er + e0);
        float4 b = *(const float4*)(er + e0 + 4);
        x[0]=a.x; x[1]=a.y; x[2]=a.z; x[3]=a.w;
        x[4]=b.x; x[5]=b.y; x[6]=b.z; x[7]=b.w;
    } else if (l == 37){
        x[0]=er[296]; x[1]=er[297]; x[2]=er[298]; x[3]=er[299];
        x[4]=0.f; x[5]=0.f; x[6]=0.f; x[7]=0.f;
    } else {
        #pragma unroll
        for (int j = 0; j < 8; j++) x[j] = 0.f;
    }
    if (l < 40){
        half8 hv;
        #pragma unroll
        for (int j = 0; j < 8; j++) hv[j] = (_Float16)x[j];
        *(half8*)(sfg + r*KP + e0) = hv;
        #pragma unroll
        for (int j = 0; j < 8; j++) mred[w][e0 + j] = x[j];
    }
    __syncthreads();
    for (int e = threadIdx.x; e < EE; e += 256){
        float s = mred[0][e] + mred[1][e] + mred[2][e] + mred[3][e];
        atomicAdd(&res[(size_t)(b0+bl)*FCIN + which*900 + e], s * (1.f/SS));
    }
}

// ---------------- mean over S of a fp16 [S,KP] tensor -> res segment --------
// grid (bc, 2), block 320   (o-means only, seg = it+1)
__global__ __launch_bounds__(320) void mean16_kernel(
    const _Float16* __restrict__ src1, const _Float16* __restrict__ src2,
    float* __restrict__ res, int b0, int seg){
    int bl = blockIdx.x, which = blockIdx.y;
    const _Float16* src = (which ? src2 : src1) + (size_t)bl*SS*KP;
    int e = threadIdx.x;
    if (e >= EE) return;
    float acc = 0.f;
    #pragma unroll 4
    for (int r = 0; r < SS; r++) acc += (float)src[r*KP + e];
    res[(size_t)(b0+bl)*FCIN + which*900 + seg*300 + e] = acc * (1.f/SS);
}

// ---------------- MFMA match (A-producing): stages sf16*v, self-computes norms
// block 512 (8 waves); wave = 16 rows x 128 cols. Writes Ab AND AbT (so the
// downstream f kernel reads both A and A^T row-major, no LDS transpose).
__global__ __launch_bounds__(512, 4) void cross_matchA(
    const _Float16* __restrict__ sfA, const _Float16* __restrict__ sfB,
    const float* __restrict__ vAg, const float* __restrict__ vBg,
    _Float16* __restrict__ Ab16, _Float16* __restrict__ AbT16)
{
    __shared__ _Float16 As[128][40];
    __shared__ _Float16 Bs[128][40];
    __shared__ float nAl[128], nBl[128], vAl[128], vBl[128];

    int bl = blockIdx.x;
    int tid = threadIdx.x;
    int w = tid >> 6, lane = tid & 63;
    int m = lane & 15, quad = lane >> 4;

    const _Float16* gA = sfA + (size_t)bl*SS*KP;
    const _Float16* gB = sfB + (size_t)bl*SS*KP;

    if (tid < 128){ vAl[tid] = vAg[bl*SS + tid]; }
    else if (tid < 256){ vBl[tid-128] = vBg[bl*SS + tid-128]; }

    f32x4 acc[8];
    #pragma unroll
    for (int c = 0; c < 8; c++) acc[c] = (f32x4){0.f,0.f,0.f,0.f};

    int srow = tid >> 2, skq = (tid & 3) * 8;
    int arow = w*16 + m;
    float nA = 0.f, nB = 0.f;

    for (int kc = 0; kc < 10; kc++){
        __syncthreads();
        {
            half8 ha = *(const half8*)(gA + srow*KP + kc*32 + skq);
            half8 hb = *(const half8*)(gB + srow*KP + kc*32 + skq);
            ha = ha * (_Float16)vAl[srow];
            hb = hb * (_Float16)vBl[srow];
            *(half8*)&As[srow][skq] = ha;
            *(half8*)&Bs[srow][skq] = hb;
            nA = norm8(ha, nA);
            nB = norm8(hb, nB);
        }
        __syncthreads();
        half8 a = *(const half8*)&As[arow][quad*8];
        #pragma unroll
        for (int c = 0; c < 8; c++){
            half8 b = *(const half8*)&Bs[c*16 + m][quad*8];
            acc[c] = __builtin_amdgcn_mfma_f32_16x16x32_f16(a, b, acc[c], 0, 0, 0);
        }
    }

    nA += __shfl_xor(nA, 1); nA += __shfl_xor(nA, 2);
    nB += __shfl_xor(nB, 1); nB += __shfl_xor(nB, 2);
    if ((tid & 3) == 0){ nAl[srow] = nA; nBl[srow] = nB; }
    __syncthreads();

    int ibase = w*16 + quad*4;
    _Float16* Ao = Ab16 + (size_t)bl*SS*SS;
    _Float16* AoT = AbT16 + (size_t)bl*SS*SS;
    #pragma unroll
    for (int c = 0; c < 8; c++){
        int j = c*16 + m;
        float nc = nBl[j];
        #pragma unroll
        for (int r = 0; r < 4; r++){
            int i = ibase + r;
            float d2 = nAl[i] + nc - 2.f*acc[c][r];
            float d = sqrtf(fmaxf(d2, 0.f));
            _Float16 val = (_Float16)(1.f / (1.f + d));
            Ao[i*SS + j] = val;
            AoT[j*SS + i] = val;
        }
    }
}

// ---------------- MFMA match sums + fused pool/residual (norms self-computed)
// block 512; after w1/w2 (LDS), parallel epilogue: sf += avg3(o*w)
__global__ __launch_bounds__(512, 4) void cross_sums_pool(
    const _Float16* __restrict__ oA, const _Float16* __restrict__ oB,
    const float* __restrict__ vAg, const float* __restrict__ vBg,
    _Float16* __restrict__ sf1, _Float16* __restrict__ sf2)
{
    __shared__ _Float16 As[128][40];
    __shared__ _Float16 Bs[128][40];
    __shared__ float nAl[128], nBl[128], vAl[128], vBl[128];
    __shared__ float colred[8][132];
    __shared__ float wr[128], wc[128];

    int bl = blockIdx.x;
    int tid = threadIdx.x;
    int w = tid >> 6, lane = tid & 63;
    int m = lane & 15, quad = lane >> 4;

    const _Float16* gA = oA + (size_t)bl*SS*KP;
    const _Float16* gB = oB + (size_t)bl*SS*KP;

    if (tid < 128){ vAl[tid] = vAg[bl*SS + tid]; }
    else if (tid < 256){ vBl[tid-128] = vBg[bl*SS + tid-128]; }

    f32x4 acc[8];
    #pragma unroll
    for (int c = 0; c < 8; c++) acc[c] = (f32x4){0.f,0.f,0.f,0.f};

    int srow = tid >> 2, skq = (tid & 3) * 8;
    int arow = w*16 + m;
    float nA = 0.f, nB = 0.f;

    for (int kc = 0; kc < 10; kc++){
        __syncthreads();
        {
            half8 ha = *(const half8*)(gA + srow*KP + kc*32 + skq);
            half8 hb = *(const half8*)(gB + srow*KP + kc*32 + skq);
            ha = ha * (_Float16)vAl[srow];
            hb = hb * (_Float16)vBl[srow];
            *(half8*)&As[srow][skq] = ha;
            *(half8*)&Bs[srow][skq] = hb;
            nA = norm8(ha, nA);
            nB = norm8(hb, nB);
        }
        __syncthreads();
        half8 a = *(const half8*)&As[arow][quad*8];
        #pragma unroll
        for (int c = 0; c < 8; c++){
            half8 b = *(const half8*)&Bs[c*16 + m][quad*8];
            acc[c] = __builtin_amdgcn_mfma_f32_16x16x32_f16(a, b, acc[c], 0, 0, 0);
        }
    }

    nA += __shfl_xor(nA, 1); nA += __shfl_xor(nA, 2);
    nB += __shfl_xor(nB, 1); nB += __shfl_xor(nB, 2);
    if ((tid & 3) == 0){ nAl[srow] = nA; nBl[srow] = nB; }
    __syncthreads();

    int ibase = w*16 + quad*4;
    float aval[8][4];
    #pragma unroll
    for (int c = 0; c < 8; c++){
        float nc = nBl[c*16 + m];
        #pragma unroll
        for (int r = 0; r < 4; r++){
            float d2 = nAl[ibase+r] + nc - 2.f*acc[c][r];
            float d = sqrtf(fmaxf(d2, 0.f));
            aval[c][r] = 1.f / (1.f + d);
        }
    }

    // row sums -> wr
    float rp[4];
    #pragma unroll
    for (int r = 0; r < 4; r++){
        float s = 0.f;
        #pragma unroll
        for (int c = 0; c < 8; c++) s += aval[c][r];
        rp[r] = s;
    }
    #pragma unroll
    for (int mask = 1; mask < 16; mask <<= 1)
        #pragma unroll
        for (int r = 0; r < 4; r++) rp[r] += __shfl_xor(rp[r], mask);
    if (m == 0){
        #pragma unroll
        for (int r = 0; r < 4; r++) wr[ibase + r] = rp[r];
    }
    // col sums -> wc
    float cp[8];
    #pragma unroll
    for (int c = 0; c < 8; c++){
        float s = 0.f;
        #pragma unroll
        for (int r = 0; r < 4; r++) s += aval[c][r];
        cp[c] = s;
    }
    #pragma unroll
    for (int c = 0; c < 8; c++){
        cp[c] += __shfl_xor(cp[c], 16);
        cp[c] += __shfl_xor(cp[c], 32);
    }
    if (quad == 0){
        #pragma unroll
        for (int c = 0; c < 8; c++) colred[w][c*16 + m] = cp[c];
    }
    __syncthreads();
    if (tid < 128){
        float s = 0.f;
        #pragma unroll
        for (int g = 0; g < 8; g++) s += colred[g][tid];
        wc[tid] = s;
    }
    __syncthreads();

    // ---- fused pool epilogue: 4 lanes per row (tid>>2 = row, tid&3 = sub) ----
    int prow = tid >> 2, sub = tid & 3;
    #pragma unroll
    for (int which = 0; which < 2; which++){
        const _Float16* og = which ? gB : gA;
        const float* wv = which ? wc : wr;
        _Float16* sg = (which ? sf2 : sf1) + (size_t)bl*SS*KP;
        float w0 = wv[prow];
        float wm = (prow > 0)   ? wv[prow-1] : 0.f;
        float wp = (prow < 127) ? wv[prow+1] : 0.f;
        #pragma unroll
        for (int k = 0; k < 10; k++){
            int e0 = (sub + k*4) * 8;           // < 320
            half8 o0 = *(const half8*)(og + prow*KP + e0);
            half8 om = {};
            half8 op = {};
            if (prow > 0)   om = *(const half8*)(og + (prow-1)*KP + e0);
            if (prow < 127) op = *(const half8*)(og + (prow+1)*KP + e0);
            half8 sv = *(const half8*)(sg + prow*KP + e0);
            half8 outh;
            #pragma unroll
            for (int j = 0; j < 8; j++){
                float a = (float)o0[j]*w0 + (float)om[j]*wm + (float)op[j]*wp;
                float ns = (float)sv[j] + a * (1.f/3.f);
                outh[j] = (_Float16)ns;
            }
            *(half8*)(sg + prow*KP + e0) = outh;
        }
    }
}

// ---------------- fused f = A@W (zz=0, from Ab) / A^T@W (zz=1, from AbT) -----
// -> full 300-col f tile in swizzled LDS -> conv3x3 + tanh -> o16.
// grid (bc, 2), block 512 (8 waves x 16 rows). A frags read DIRECT from global
// (both operands row-major over their k dim); f never touches HBM; each block
// writes complete o16 rows (coalesced, no cross-block cache lines).
__global__ __launch_bounds__(512, 4) void f_conv_kernel(
    const _Float16* __restrict__ Ab, const _Float16* __restrict__ AbT,
    const _Float16* __restrict__ Wt,
    const _Float16* __restrict__ sf1, const _Float16* __restrict__ sf2,
    const float* __restrict__ pw,
    _Float16* __restrict__ o16_1, _Float16* __restrict__ o16_2)
{
    __shared__ _Float16 ftile[128*320];          // 80 KB, fswz layout

    int bl = blockIdx.x, zz = blockIdx.y;
    int tid = threadIdx.x, w = tid >> 6, lane = tid & 63;
    int m = lane & 15, quad = lane >> 4;

    // conv weights (uniform loads)
    const unsigned* pu = (const unsigned*)pw;
    h2 w01[2][3], w12[2][3];
    float w0f[2][3], w2f[2][3];
    #pragma unroll
    for (int c = 0; c < 2; c++)
        #pragma unroll
        for (int dy = 0; dy < 3; dy++){
            int rem = c*3 + dy;
            w01[c][dy] = __builtin_bit_cast(h2, pu[rem]);
            w12[c][dy] = __builtin_bit_cast(h2, pu[6 + rem]);
            w0f[c][dy] = pw[12 + rem];
            w2f[c][dy] = pw[18 + rem];
        }
    float bias = pw[24];

    // ---- phase 1: f = A(T) @ W, c-outer, acc streamed to swizzled LDS ----
    const _Float16* gA = (zz ? AbT : Ab) + (size_t)bl*SS*SS;
    int arow = w*16 + m;
    half8 a[4];
    #pragma unroll
    for (int kc = 0; kc < 4; kc++)
        a[kc] = *(const half8*)(gA + arow*SS + kc*32 + quad*8);

    #pragma unroll
    for (int c = 0; c < 19; c++){
        int e = c*16 + m;                        // 0..303
        f32x4 acc = (f32x4){0.f,0.f,0.f,0.f};
        #pragma unroll
        for (int kc = 0; kc < 4; kc++){
            half8 b = *(const half8*)(Wt + (size_t)e*SS + kc*32 + quad*8);
            acc = __builtin_amdgcn_mfma_f32_16x16x32_f16(a[kc], b, acc, 0, 0, 0);
        }
        bool ev = (e < EE);
        #pragma unroll
        for (int r = 0; r < 4; r++){
            int i = w*16 + quad*4 + r;
            ftile[fswz(i, e)] = ev ? (_Float16)acc[r] : (_Float16)0.f;
        }
    }
    // zero-fill cols 304..319 (uniform padding for the conv phase)
    {
        int zr = tid >> 2, zc0 = 304 + (tid & 3)*4;
        #pragma unroll
        for (int j = 0; j < 4; j++) ftile[fswz(zr, zc0 + j)] = (_Float16)0.f;
    }
    __syncthreads();

    // ---- phase 2: conv(3x3, ch0=sf global, ch1=f LDS) + tanh -> o16 ----
    int rr = tid >> 2, seg = tid & 3;
    const _Float16* cs = (zz ? sf2 : sf1) + (size_t)bl*SS*KP;
    _Float16* od = (zz ? o16_2 : o16_1) + (size_t)bl*SS*KP;

    #pragma unroll
    for (int p = 0; p < 2; p++){
        int cb = seg*80 + p*40;                  // 40 output cols per pass
        float cacc[5][8];
        #pragma unroll
        for (int k = 0; k < 5; k++)
            #pragma unroll
            for (int j = 0; j < 8; j++) cacc[k][j] = bias;

        #pragma unroll
        for (int c = 0; c < 2; c++){
            #pragma unroll
            for (int dy = 0; dy < 3; dy++){
                int gr = rr + dy - 1;
                bool rok = (gr >= 0) && (gr < SS);
                half8 d[5];
                float L = 0.f, R = 0.f;
                #pragma unroll
                for (int k = 0; k < 5; k++) d[k] = (half8){};
                if (rok){
                    if (c == 0){
                        #pragma unroll
                        for (int k = 0; k < 5; k++)
                            d[k] = *(const half8*)(cs + gr*KP + cb + k*8);
                        if (cb > 0)       L = (float)cs[gr*KP + cb - 1];
                        if (cb + 40 < KP) R = (float)cs[gr*KP + cb + 40];
                    } else {
                        #pragma unroll
                        for (int k = 0; k < 5; k++)
                            d[k] = *(const half8*)&ftile[fswz(gr, cb + k*8)];
                        if (cb > 0)        L = (float)ftile[fswz(gr, cb - 1)];
                        if (cb + 40 < 320) R = (float)ftile[fswz(gr, cb + 40)];
                    }
                }
                h2 W01 = w01[c][dy], W12 = w12[c][dy];
                float W0 = w0f[c][dy], W2 = w2f[c][dy];
                #pragma unroll
                for (int k = 0; k < 5; k++){
                    float xm = (k == 0) ? L : (float)d[k-1][7];
                    float xp = (k == 4) ? R : (float)d[k+1][0];
                    h2 p0 = __builtin_shufflevector(d[k], d[k], 0, 1);
                    h2 p1 = __builtin_shufflevector(d[k], d[k], 2, 3);
                    h2 p2 = __builtin_shufflevector(d[k], d[k], 4, 5);
                    h2 p3 = __builtin_shufflevector(d[k], d[k], 6, 7);
                    cacc[k][0] = __builtin_amdgcn_fdot2(W12, p0, cacc[k][0], false);
                    cacc[k][0] = fmaf(W0, xm, cacc[k][0]);
                    cacc[k][1] = __builtin_amdgcn_fdot2(W01, p0, cacc[k][1], false);
                    cacc[k][1] = fmaf(W2, (float)d[k][2], cacc[k][1]);
                    cacc[k][2] = __builtin_amdgcn_fdot2(W12, p1, cacc[k][2], false);
                    cacc[k][2] = fmaf(W0, (float)d[k][1], cacc[k][2]);
                    cacc[k][3] = __builtin_amdgcn_fdot2(W01, p1, cacc[k][3], false);
                    cacc[k][3] = fmaf(W2, (float)d[k][4], cacc[k][3]);
                    cacc[k][4] = __builtin_amdgcn_fdot2(W12, p2, cacc[k][4], false);
                    cacc[k][4] = fmaf(W0, (float)d[k][3], cacc[k][4]);
                    cacc[k][5] = __builtin_amdgcn_fdot2(W01, p2, cacc[k][5], false);
                    cacc[k][5] = fmaf(W2, (float)d[k][6], cacc[k][5]);
                    cacc[k][6] = __builtin_amdgcn_fdot2(W12, p3, cacc[k][6], false);
                    cacc[k][6] = fmaf(W0, (float)d[k][5], cacc[k][6]);
                    cacc[k][7] = __builtin_amdgcn_fdot2(W01, p3, cacc[k][7], false);
                    cacc[k][7] = fmaf(W2, xp, cacc[k][7]);
                }
            }
        }

        #pragma unroll
        for (int k = 0; k < 5; k++){
            half8 outh;
            #pragma unroll
            for (int j = 0; j < 8; j++){
                int e = cb + k*8 + j;
                float t = (e < EE) ? fast_tanh(cacc[k][j]) : 0.f;
                outh[j] = (_Float16)t;
            }
            *(half8*)(od + rr*KP + cb + k*8) = outh;
        }
    }
}

// ---------------- fc1: K-split x6, atomic accumulate into h ------------------
// grid (8,5,6), block 256; h must be zeroed before launch
#define CKK 12
__global__ __launch_bounds__(256) void fc1_kernel(const float* __restrict__ res,
                                                  const float* __restrict__ fw,
                                                  float* __restrict__ h){
    __shared__ float Xt[CKK][68];
    __shared__ float Wts[CKK][68];
    int bt = blockIdx.x, jt = blockIdx.y, kz = blockIdx.z;
    int tid = threadIdx.x, tx = tid & 15, ty = tid >> 4;
    int b0l = bt*64, j0 = jt*64, kbase = kz*300;
    float acc[4][4] = {};
    for (int k0 = 0; k0 < 300; k0 += CKK){
        #pragma unroll
        for (int u = 0; u < 3; u++){
            int idx = tid + u*256;
            int a = idx / CKK, k = idx - a*CKK;
            Xt[k][a] = res[(size_t)(b0l+a)*FCIN + kbase + k0 + k];
            int gj = j0 + a;
            Wts[k][a] = (gj < HH) ? fw[(size_t)gj*FCIN + kbase + k0 + k] : 0.f;
        }
        __syncthreads();
        #pragma unroll
        for (int k = 0; k < CKK; k++){
            float xv[4], wv[4];
            #pragma unroll
            for (int r = 0; r < 4; r++) xv[r] = Xt[k][ty*4+r];
            #pragma unroll
            for (int c = 0; c < 4; c++) wv[c] = Wts[k][tx*4+c];
            #pragma unroll
            for (int r = 0; r < 4; r++)
                #pragma unroll
                for (int c = 0; c < 4; c++)
                    acc[r][c] = fmaf(xv[r], wv[c], acc[r][c]);
        }
        __syncthreads();
    }
    #pragma unroll
    for (int r = 0; r < 4; r++){
        int gb = b0l + ty*4 + r;
        #pragma unroll
        for (int c = 0; c < 4; c++){
            int gj = j0 + tx*4 + c;
            if (gj < HH) atomicAdd(&h[(size_t)gb*HH + gj], acc[r][c]);
        }
    }
}

// ---------------- layernorm + relu + fc2 + softmax (+fc1 bias) ---------------
__global__ void head_kernel(const float* __restrict__ h, const float* __restrict__ fb,
                            const float* __restrict__ g,
                            const float* __restrict__ be, const float* __restrict__ f2w,
                            const float* __restrict__ f2b, float* __restrict__ out){
    int b = blockIdx.x, tid = threadIdx.x;
    __shared__ float arr[HH];
    __shared__ float s_s[4], s_q[4], r0[4], r1[4];
    float x0 = (tid < HH) ? h[(size_t)b*HH + tid] + fb[tid] : 0.f;
    float x1 = (tid + 256 < HH) ? h[(size_t)b*HH + tid + 256] + fb[tid+256] : 0.f;
    float s = x0 + x1, sq = x0*x0 + x1*x1;
    #pragma unroll
    for (int o = 32; o > 0; o >>= 1){ s += __shfl_down(s, o); sq += __shfl_down(sq, o); }
    int wv = tid >> 6, ln = tid & 63;
    if (ln == 0){ s_s[wv] = s; s_q[wv] = sq; }
    __syncthreads();
    s  = s_s[0] + s_s[1] + s_s[2] + s_s[3];
    sq = s_q[0] + s_q[1] + s_q[2] + s_q[3];
    float mean = s / HH;
    float var = sq / HH - mean*mean;
    float inv = rsqrtf(var + 1e-5f);
    if (tid < HH)       arr[tid]     = fmaxf((x0 - mean)*inv*g[tid]     + be[tid],     0.f);
    if (tid + 256 < HH) arr[tid+256] = fmaxf((x1 - mean)*inv*g[tid+256] + be[tid+256], 0.f);
    __syncthreads();
    float p0 = 0.f, p1 = 0.f;
    for (int j = tid; j < HH; j += 256){ float hv = arr[j]; p0 += hv*f2w[j]; p1 += hv*f2w[HH+j]; }
    #pragma unroll
    for (int o = 32; o > 0; o >>= 1){ p0 += __shfl_down(p0, o); p1 += __shfl_down(p1, o); }
    if (ln == 0){ r0[wv] = p0; r1[wv] = p1; }
    __syncthreads();
    if (tid == 0){
        float o0 = r0[0]+r0[1]+r0[2]+r0[3] + f2b[0];
        float o1 = r1[0]+r1[1]+r1[2]+r1[3] + f2b[1];
        out[b*2+0] = o0; out[b*2+1] = o1;
        float m = fmaxf(o0, o1);
        float e0 = __expf(o0 - m), e1 = __expf(o1 - m);
        float den = e0 + e1;
        out[BB*2 + b*2+0] = e0/den;
        out[BB*2 + b*2+1] = e1/den;
    }
}

extern "C" void kernel_launch(void* const* d_in, const int* in_sizes, int n_in,
                              void* d_out, int out_size, void* d_ws, size_t ws_size,
                              hipStream_t stream){
    const int*   seq1   = (const int*)d_in[0];
    const int*   seq2   = (const int*)d_in[1];
    const float* emb    = (const float*)d_in[2];
    const float* W      = (const float*)d_in[3];
    const float* conv_w = (const float*)d_in[4];
    const float* conv_b = (const float*)d_in[5];
    const float* fc1_w  = (const float*)d_in[6];
    const float* fc1_b  = (const float*)d_in[7];
    const float* ln_g   = (const float*)d_in[8];
    const float* ln_b   = (const float*)d_in[9];
    const float* fc2_w  = (const float*)d_in[10];
    const float* fc2_b  = (const float*)d_in[11];
    float* out = (float*)d_out;

    float* ws = (float*)d_ws;
    size_t fixedf = (size_t)BB*FCIN + (size_t)BB*HH + (size_t)KP*SS + 64;
    // per-batch floats: sf16 + o16 (each 2*SS*KP halves) + Ab + AbT + 2 vecs
    size_t perb = (size_t)2*SS*KP + (size_t)(SS*SS) + 2*SS;
    size_t avail = ws_size / 4;
    long long bcl = (long long)((avail > fixedf ? avail - fixedf : 0) / perb);
    int BC = (int)(bcl < 1 ? 1 : (bcl > BB ? BB : bcl));

    float* res = ws;
    float* hb  = res + (size_t)BB*FCIN;
    _Float16* Wt = (_Float16*)(hb + (size_t)BB*HH);
    float* pwt = (float*)(Wt + (size_t)2*KP*SS);
    _Float16* sf1 = (_Float16*)(pwt + 64);
    _Float16* sf2 = sf1 + (size_t)BC*SS*KP;
    _Float16* o16_1 = sf2 + (size_t)BC*SS*KP;
    _Float16* o16_2 = o16_1 + (size_t)BC*SS*KP;
    _Float16* Ab  = o16_2 + (size_t)BC*SS*KP;
    _Float16* AbT = Ab + (size_t)BC*SS*SS;
    float* v1  = (float*)(AbT + (size_t)BC*SS*SS);
    float* v2  = v1 + (size_t)BC*SS;

    wt_build_kernel<<<(2*KP*SS + 255)/256, 256, 0, stream>>>(W, Wt);
    cwpack_kernel<<<1, 64, 0, stream>>>(conv_w, conv_b, pwt);
    hipMemsetAsync(hb, 0, (size_t)BB*HH*sizeof(float), stream);
    hipMemsetAsync(res, 0, (size_t)BB*FCIN*sizeof(float), stream);

    for (int b0 = 0; b0 < BB; b0 += BC){
        int bc = (BB - b0 < BC) ? (BB - b0) : BC;
        embed_kernel<<<dim3(bc, 32, 2), 256, 0, stream>>>(seq1, seq2, emb, sf1, sf2,
                                                          v1, v2, res, b0);
        for (int it = 0; it < LLI; it++){
            cross_matchA<<<bc, 512, 0, stream>>>(sf1, sf2, v1, v2, Ab, AbT);
            f_conv_kernel<<<dim3(bc, 2), 512, 0, stream>>>(Ab, AbT, Wt + (size_t)it*KP*SS,
                                                           sf1, sf2, pwt + it*32,
                                                           o16_1, o16_2);
            mean16_kernel<<<dim3(bc, 2), 320, 0, stream>>>(o16_1, o16_2, res, b0, it+1);
            cross_sums_pool<<<bc, 512, 0, stream>>>(o16_1, o16_2, v1, v2, sf1, sf2);
        }
    }
    fc1_kernel<<<dim3(8, 5, 6), 256, 0, stream>>>(res, fc1_w, hb);
    head_kernel<<<BB, 256, 0, stream>>>(hb, fc1_b, ln_g, ln_b, fc2_w, fc2_b, out);
}

// Round 6
// 817.540 us; speedup vs baseline: 1.1157x; 1.1157x over previous
//
#include <hip/hip_runtime.h>
#include <math.h>

#define BB 512
#define SS 128
#define EE 300
#define HH 300
#define FCIN 1800
#define LLI 2
#define KP 320          // padded K / leading dim for fp16 tensors

using half8 = __attribute__((ext_vector_type(8))) _Float16;
using h2    = __attribute__((ext_vector_type(2))) _Float16;
using f32x4 = __attribute__((ext_vector_type(4))) float;

__device__ __forceinline__ float fast_tanh(float x){
    float ax = fabsf(x);
    float t = __expf(-2.f*ax);
    float r = (1.f - t) / (1.f + t);
    return copysignf(r, x);
}

// norm accumulate of a half8 via 4 fdot2 (constant-index pair extraction)
__device__ __forceinline__ float norm8(half8 hv, float n){
    h2 p0 = __builtin_shufflevector(hv, hv, 0, 1);
    h2 p1 = __builtin_shufflevector(hv, hv, 2, 3);
    h2 p2 = __builtin_shufflevector(hv, hv, 4, 5);
    h2 p3 = __builtin_shufflevector(hv, hv, 6, 7);
    n = __builtin_amdgcn_fdot2(p0, p0, n, false);
    n = __builtin_amdgcn_fdot2(p1, p1, n, false);
    n = __builtin_amdgcn_fdot2(p2, p2, n, false);
    n = __builtin_amdgcn_fdot2(p3, p3, n, false);
    return n;
}

// ---------------- Wt build: Wt[it][e][j] = W[it][j][e], fp16, e zero-padded to 320
__global__ void wt_build_kernel(const float* __restrict__ W, _Float16* __restrict__ Wt){
    int idx = blockIdx.x*256 + threadIdx.x;      // 2*320*128 = 81920
    if (idx >= 2*KP*SS) return;
    int j = idx & 127;
    int e = (idx >> 7) % KP;
    int it = idx / (KP*SS);
    float v = (e < EE) ? W[(size_t)it*SS*EE + j*EE + e] : 0.f;
    Wt[idx] = (_Float16)v;
}

// ---------------- pack conv weights: per it, 32 dwords:
// [0..5] h2(w0,w1) per (c,dy); [6..11] h2(w1,w2); [12..17] f32 w0; [18..23] f32 w2; [24] bias
__global__ void cwpack_kernel(const float* __restrict__ cw, const float* __restrict__ cb,
                              float* __restrict__ pwt){
    int t = threadIdx.x;
    if (t < 12){
        int it = t / 6, rem = t % 6;          // rem = c*3+dy
        const float* w = cw + it*18 + rem*3;
        float a = w[0], b = w[1], d = w[2];
        h2 p01 = { (_Float16)a, (_Float16)b };
        h2 p12 = { (_Float16)b, (_Float16)d };
        float* o = pwt + it*32;
        ((unsigned*)o)[rem]   = __builtin_bit_cast(unsigned, p01);
        ((unsigned*)o)[6+rem] = __builtin_bit_cast(unsigned, p12);
        o[12+rem] = a;
        o[18+rem] = d;
    }
    if (t < 2) pwt[t*32+24] = cb[t];
}

// ---------------- embed: gather -> sf16 + valid mask + fused seg-0 mean ------
// grid (bc, 32, 2), block 256 (4 waves, wave = 1 row); res must be zeroed
__global__ __launch_bounds__(256) void embed_kernel(
    const int* __restrict__ seq1, const int* __restrict__ seq2,
    const float* __restrict__ emb,
    _Float16* __restrict__ sf1, _Float16* __restrict__ sf2,
    float* __restrict__ v1, float* __restrict__ v2,
    float* __restrict__ res, int b0){
    __shared__ float mred[4][320];
    int bl = blockIdx.x, which = blockIdx.z;
    int w = threadIdx.x >> 6;
    int r = blockIdx.y*4 + w;
    int l = threadIdx.x & 63;
    const int* seq = which ? seq2 : seq1;
    _Float16* sfg = (which ? sf2 : sf1) + (size_t)bl*SS*KP;
    float* vd = (which ? v2 : v1) + bl*SS;
    int token = seq[(size_t)(b0+bl)*SS + r];
    if (l == 0) vd[r] = (token != 0) ? 1.f : 0.f;
    const float* er = emb + (size_t)token * EE;
    int e0 = l*8;
    float x[8];
    if (l < 37){
        float4 a = *(const float4*)(er + e0);
        float4 b = *(const float4*)(er + e0 + 4);
        x[0]=a.x; x[1]=a.y; x[2]=a.z; x[3]=a.w;
        x[4]=b.x; x[5]=b.y; x[6]=b.z; x[7]=b.w;
    } else if (l == 37){
        x[0]=er[296]; x[1]=er[297]; x[2]=er[298]; x[3]=er[299];
        x[4]=0.f; x[5]=0.f; x[6]=0.f; x[7]=0.f;
    } else {
        #pragma unroll
        for (int j = 0; j < 8; j++) x[j] = 0.f;
    }
    if (l < 40){
        half8 hv;
        #pragma unroll
        for (int j = 0; j < 8; j++) hv[j] = (_Float16)x[j];
        *(half8*)(sfg + r*KP + e0) = hv;
        #pragma unroll
        for (int j = 0; j < 8; j++) mred[w][e0 + j] = x[j];
    }
    __syncthreads();
    for (int e = threadIdx.x; e < EE; e += 256){
        float s = mred[0][e] + mred[1][e] + mred[2][e] + mred[3][e];
        atomicAdd(&res[(size_t)(b0+bl)*FCIN + which*900 + e], s * (1.f/SS));
    }
}

// ---------------- mean over S of a fp16 [S,KP] tensor -> res segment --------
// grid (bc, 2), block 320   (o-means only, seg = it+1)
__global__ __launch_bounds__(320) void mean16_kernel(
    const _Float16* __restrict__ src1, const _Float16* __restrict__ src2,
    float* __restrict__ res, int b0, int seg){
    int bl = blockIdx.x, which = blockIdx.y;
    const _Float16* src = (which ? src2 : src1) + (size_t)bl*SS*KP;
    int e = threadIdx.x;
    if (e >= EE) return;
    float acc = 0.f;
    #pragma unroll 4
    for (int r = 0; r < SS; r++) acc += (float)src[r*KP + e];
    res[(size_t)(b0+bl)*FCIN + which*900 + seg*300 + e] = acc * (1.f/SS);
}

// ---------------- MFMA match (A-producing): stages sf16*v, self-computes norms
// block 512 (8 waves); wave = 16 rows x 128 cols. Writes Ab AND AbT (so the
// downstream f kernel reads both A and A^T row-major, no LDS transpose).
__global__ __launch_bounds__(512, 4) void cross_matchA(
    const _Float16* __restrict__ sfA, const _Float16* __restrict__ sfB,
    const float* __restrict__ vAg, const float* __restrict__ vBg,
    _Float16* __restrict__ Ab16, _Float16* __restrict__ AbT16)
{
    __shared__ _Float16 As[128][40];
    __shared__ _Float16 Bs[128][40];
    __shared__ float nAl[128], nBl[128], vAl[128], vBl[128];

    int bl = blockIdx.x;
    int tid = threadIdx.x;
    int w = tid >> 6, lane = tid & 63;
    int m = lane & 15, quad = lane >> 4;

    const _Float16* gA = sfA + (size_t)bl*SS*KP;
    const _Float16* gB = sfB + (size_t)bl*SS*KP;

    if (tid < 128){ vAl[tid] = vAg[bl*SS + tid]; }
    else if (tid < 256){ vBl[tid-128] = vBg[bl*SS + tid-128]; }

    f32x4 acc[8];
    #pragma unroll
    for (int c = 0; c < 8; c++) acc[c] = (f32x4){0.f,0.f,0.f,0.f};

    int srow = tid >> 2, skq = (tid & 3) * 8;
    int arow = w*16 + m;
    float nA = 0.f, nB = 0.f;

    for (int kc = 0; kc < 10; kc++){
        __syncthreads();
        {
            half8 ha = *(const half8*)(gA + srow*KP + kc*32 + skq);
            half8 hb = *(const half8*)(gB + srow*KP + kc*32 + skq);
            ha = ha * (_Float16)vAl[srow];
            hb = hb * (_Float16)vBl[srow];
            *(half8*)&As[srow][skq] = ha;
            *(half8*)&Bs[srow][skq] = hb;
            nA = norm8(ha, nA);
            nB = norm8(hb, nB);
        }
        __syncthreads();
        half8 a = *(const half8*)&As[arow][quad*8];
        #pragma unroll
        for (int c = 0; c < 8; c++){
            half8 b = *(const half8*)&Bs[c*16 + m][quad*8];
            acc[c] = __builtin_amdgcn_mfma_f32_16x16x32_f16(a, b, acc[c], 0, 0, 0);
        }
    }

    nA += __shfl_xor(nA, 1); nA += __shfl_xor(nA, 2);
    nB += __shfl_xor(nB, 1); nB += __shfl_xor(nB, 2);
    if ((tid & 3) == 0){ nAl[srow] = nA; nBl[srow] = nB; }
    __syncthreads();

    int ibase = w*16 + quad*4;
    _Float16* Ao = Ab16 + (size_t)bl*SS*SS;
    _Float16* AoT = AbT16 + (size_t)bl*SS*SS;
    #pragma unroll
    for (int c = 0; c < 8; c++){
        int j = c*16 + m;
        float nc = nBl[j];
        #pragma unroll
        for (int r = 0; r < 4; r++){
            int i = ibase + r;
            float d2 = nAl[i] + nc - 2.f*acc[c][r];
            float d = sqrtf(fmaxf(d2, 0.f));
            _Float16 val = (_Float16)(1.f / (1.f + d));
            Ao[i*SS + j] = val;
            AoT[j*SS + i] = val;
        }
    }
}

// ---------------- MFMA match sums + fused pool/residual (norms self-computed)
// block 512; after w1/w2 (LDS), parallel epilogue: sf += avg3(o*w)
__global__ __launch_bounds__(512, 4) void cross_sums_pool(
    const _Float16* __restrict__ oA, const _Float16* __restrict__ oB,
    const float* __restrict__ vAg, const float* __restrict__ vBg,
    _Float16* __restrict__ sf1, _Float16* __restrict__ sf2)
{
    __shared__ _Float16 As[128][40];
    __shared__ _Float16 Bs[128][40];
    __shared__ float nAl[128], nBl[128], vAl[128], vBl[128];
    __shared__ float colred[8][132];
    __shared__ float wr[128], wc[128];

    int bl = blockIdx.x;
    int tid = threadIdx.x;
    int w = tid >> 6, lane = tid & 63;
    int m = lane & 15, quad = lane >> 4;

    const _Float16* gA = oA + (size_t)bl*SS*KP;
    const _Float16* gB = oB + (size_t)bl*SS*KP;

    if (tid < 128){ vAl[tid] = vAg[bl*SS + tid]; }
    else if (tid < 256){ vBl[tid-128] = vBg[bl*SS + tid-128]; }

    f32x4 acc[8];
    #pragma unroll
    for (int c = 0; c < 8; c++) acc[c] = (f32x4){0.f,0.f,0.f,0.f};

    int srow = tid >> 2, skq = (tid & 3) * 8;
    int arow = w*16 + m;
    float nA = 0.f, nB = 0.f;

    for (int kc = 0; kc < 10; kc++){
        __syncthreads();
        {
            half8 ha = *(const half8*)(gA + srow*KP + kc*32 + skq);
            half8 hb = *(const half8*)(gB + srow*KP + kc*32 + skq);
            ha = ha * (_Float16)vAl[srow];
            hb = hb * (_Float16)vBl[srow];
            *(half8*)&As[srow][skq] = ha;
            *(half8*)&Bs[srow][skq] = hb;
            nA = norm8(ha, nA);
            nB = norm8(hb, nB);
        }
        __syncthreads();
        half8 a = *(const half8*)&As[arow][quad*8];
        #pragma unroll
        for (int c = 0; c < 8; c++){
            half8 b = *(const half8*)&Bs[c*16 + m][quad*8];
            acc[c] = __builtin_amdgcn_mfma_f32_16x16x32_f16(a, b, acc[c], 0, 0, 0);
        }
    }

    nA += __shfl_xor(nA, 1); nA += __shfl_xor(nA, 2);
    nB += __shfl_xor(nB, 1); nB += __shfl_xor(nB, 2);
    if ((tid & 3) == 0){ nAl[srow] = nA; nBl[srow] = nB; }
    __syncthreads();

    int ibase = w*16 + quad*4;
    float aval[8][4];
    #pragma unroll
    for (int c = 0; c < 8; c++){
        float nc = nBl[c*16 + m];
        #pragma unroll
        for (int r = 0; r < 4; r++){
            float d2 = nAl[ibase+r] + nc - 2.f*acc[c][r];
            float d = sqrtf(fmaxf(d2, 0.f));
            aval[c][r] = 1.f / (1.f + d);
        }
    }

    // row sums -> wr
    float rp[4];
    #pragma unroll
    for (int r = 0; r < 4; r++){
        float s = 0.f;
        #pragma unroll
        for (int c = 0; c < 8; c++) s += aval[c][r];
        rp[r] = s;
    }
    #pragma unroll
    for (int mask = 1; mask < 16; mask <<= 1)
        #pragma unroll
        for (int r = 0; r < 4; r++) rp[r] += __shfl_xor(rp[r], mask);
    if (m == 0){
        #pragma unroll
        for (int r = 0; r < 4; r++) wr[ibase + r] = rp[r];
    }
    // col sums -> wc
    float cp[8];
    #pragma unroll
    for (int c = 0; c < 8; c++){
        float s = 0.f;
        #pragma unroll
        for (int r = 0; r < 4; r++) s += aval[c][r];
        cp[c] = s;
    }
    #pragma unroll
    for (int c = 0; c < 8; c++){
        cp[c] += __shfl_xor(cp[c], 16);
        cp[c] += __shfl_xor(cp[c], 32);
    }
    if (quad == 0){
        #pragma unroll
        for (int c = 0; c < 8; c++) colred[w][c*16 + m] = cp[c];
    }
    __syncthreads();
    if (tid < 128){
        float s = 0.f;
        #pragma unroll
        for (int g = 0; g < 8; g++) s += colred[g][tid];
        wc[tid] = s;
    }
    __syncthreads();

    // ---- fused pool epilogue: 4 lanes per row (tid>>2 = row, tid&3 = sub) ----
    int prow = tid >> 2, sub = tid & 3;
    #pragma unroll
    for (int which = 0; which < 2; which++){
        const _Float16* og = which ? gB : gA;
        const float* wv = which ? wc : wr;
        _Float16* sg = (which ? sf2 : sf1) + (size_t)bl*SS*KP;
        float w0 = wv[prow];
        float wm = (prow > 0)   ? wv[prow-1] : 0.f;
        float wp = (prow < 127) ? wv[prow+1] : 0.f;
        #pragma unroll
        for (int k = 0; k < 10; k++){
            int e0 = (sub + k*4) * 8;           // < 320
            half8 o0 = *(const half8*)(og + prow*KP + e0);
            half8 om = {};
            half8 op = {};
            if (prow > 0)   om = *(const half8*)(og + (prow-1)*KP + e0);
            if (prow < 127) op = *(const half8*)(og + (prow+1)*KP + e0);
            half8 sv = *(const half8*)(sg + prow*KP + e0);
            half8 outh;
            #pragma unroll
            for (int j = 0; j < 8; j++){
                float a = (float)o0[j]*w0 + (float)om[j]*wm + (float)op[j]*wp;
                float ns = (float)sv[j] + a * (1.f/3.f);
                outh[j] = (_Float16)ns;
            }
            *(half8*)(sg + prow*KP + e0) = outh;
        }
    }
}

// ---------------- fused f = A@W (zz=0) / A^T@W (zz=1, from AbT) -> LDS -------
// -> conv3x3 + tanh -> o16.  grid (bc, 4 row-strips, 2), block 256 (4 waves).
// Strip rs covers output rows [rs*32, rs*32+32); ftile holds f rows
// [rs*32-8, rs*32+40) (OOB rows zeroed) so the conv's row halo is internal.
// Phase 1: MFMA direct from global (A fetched ~1.5x, Wt L2-resident).
// Phase 2: wave=row conv (proven r3 shape): lanes 0..39, shfl col-halos,
// full-row coalesced 640B stores -> no write amplification.
__global__ __launch_bounds__(256, 5) void f_conv_kernel(
    const _Float16* __restrict__ Ab, const _Float16* __restrict__ AbT,
    const _Float16* __restrict__ Wt,
    const _Float16* __restrict__ sf1, const _Float16* __restrict__ sf2,
    const float* __restrict__ pw,
    _Float16* __restrict__ o16_1, _Float16* __restrict__ o16_2)
{
    __shared__ _Float16 ftile[48][320];          // 30 KB

    int bl = blockIdx.x, rs = blockIdx.y, zz = blockIdx.z;
    int R0 = rs*32 - 8;
    int tid = threadIdx.x, w = tid >> 6, lane = tid & 63;
    int m = lane & 15, quad = lane >> 4;

    // conv weights (uniform loads)
    const unsigned* pu = (const unsigned*)pw;
    h2 w01[2][3], w12[2][3];
    float w0f[2][3], w2f[2][3];
    #pragma unroll
    for (int c = 0; c < 2; c++)
        #pragma unroll
        for (int dy = 0; dy < 3; dy++){
            int rem = c*3 + dy;
            w01[c][dy] = __builtin_bit_cast(h2, pu[rem]);
            w12[c][dy] = __builtin_bit_cast(h2, pu[6 + rem]);
            w0f[c][dy] = pw[12 + rem];
            w2f[c][dy] = pw[18 + rem];
        }
    float bias = pw[24];

    // ---- phase 1: f rows [R0, R0+48) x cols 0..303 via MFMA ----
    const _Float16* gA = (zz ? AbT : Ab) + (size_t)bl*SS*SS;
    #pragma unroll
    for (int rg = 0; rg < 3; rg++){
        int gar = R0 + rg*16 + m;                      // A row for this lane
        int gac = gar < 0 ? 0 : (gar > SS-1 ? SS-1 : gar);   // clamp (values unused if OOB)
        half8 a[4];
        #pragma unroll
        for (int kc = 0; kc < 4; kc++)
            a[kc] = *(const half8*)(gA + gac*SS + kc*32 + quad*8);
        #pragma unroll
        for (int ci = 0; ci < 5; ci++){
            int c = w + ci*4;                          // wave-strided col frags
            if (c < 19){
                int e = c*16 + m;                      // 0..303
                f32x4 acc = (f32x4){0.f,0.f,0.f,0.f};
                #pragma unroll
                for (int kc = 0; kc < 4; kc++){
                    half8 b = *(const half8*)(Wt + (size_t)e*SS + kc*32 + quad*8);
                    acc = __builtin_amdgcn_mfma_f32_16x16x32_f16(a[kc], b, acc, 0, 0, 0);
                }
                #pragma unroll
                for (int r = 0; r < 4; r++){
                    int lr = rg*16 + quad*4 + r;
                    int gf = R0 + lr;
                    bool ok = (gf >= 0) && (gf < SS) && (e < EE);
                    ftile[lr][e] = ok ? (_Float16)acc[r] : (_Float16)0.f;
                }
            }
        }
    }
    // zero-fill cols 304..319 (uniform padding for conv)
    for (int idx = tid; idx < 48*16; idx += 256)
        ftile[idx >> 4][304 + (idx & 15)] = (_Float16)0.f;
    __syncthreads();

    // ---- phase 2: conv(3x3, ch0=sf global, ch1=f LDS) + tanh -> o16 ----
    const _Float16* cs = (zz ? sf2 : sf1) + (size_t)bl*SS*KP;
    _Float16* od = (zz ? o16_2 : o16_1) + (size_t)bl*SS*KP;
    int l = lane, e0 = l*8;
    bool lok = (l < 40);

    for (int i = 0; i < 8; i++){
        int lr = 8 + w*8 + i;                   // local f row
        int gro = rs*32 + w*8 + i;              // global output row
        float acc[8];
        #pragma unroll
        for (int j = 0; j < 8; j++) acc[j] = bias;

        #pragma unroll
        for (int c = 0; c < 2; c++){
            #pragma unroll
            for (int dy = 0; dy < 3; dy++){
                half8 hv = {};
                if (c == 0){
                    int gr = gro + dy - 1;
                    if (gr >= 0 && gr < SS && lok)
                        hv = *(const half8*)(cs + gr*KP + e0);
                } else {
                    if (lok)
                        hv = *(const half8*)&ftile[lr + dy - 1][e0];
                }
                h2 d0 = __builtin_shufflevector(hv, hv, 0, 1);
                h2 d1 = __builtin_shufflevector(hv, hv, 2, 3);
                h2 d2 = __builtin_shufflevector(hv, hv, 4, 5);
                h2 d3 = __builtin_shufflevector(hv, hv, 6, 7);
                int dmi = __shfl_up(__builtin_bit_cast(int, d3), 1);
                int dpi = __shfl_down(__builtin_bit_cast(int, d0), 1);
                h2 dmh = __builtin_bit_cast(h2, dmi);
                h2 dph = __builtin_bit_cast(h2, dpi);
                float xm = (l == 0) ? 0.f : (float)dmh[1];
                float xp = (float)dph[0];
                h2 W01 = w01[c][dy], W12 = w12[c][dy];
                float W0 = w0f[c][dy], W2 = w2f[c][dy];
                acc[0] = __builtin_amdgcn_fdot2(W12, d0, acc[0], false);
                acc[0] = fmaf(W0, xm, acc[0]);
                acc[1] = __builtin_amdgcn_fdot2(W01, d0, acc[1], false);
                acc[1] = fmaf(W2, (float)d1[0], acc[1]);
                acc[2] = __builtin_amdgcn_fdot2(W12, d1, acc[2], false);
                acc[2] = fmaf(W0, (float)d0[1], acc[2]);
                acc[3] = __builtin_amdgcn_fdot2(W01, d1, acc[3], false);
                acc[3] = fmaf(W2, (float)d2[0], acc[3]);
                acc[4] = __builtin_amdgcn_fdot2(W12, d2, acc[4], false);
                acc[4] = fmaf(W0, (float)d1[1], acc[4]);
                acc[5] = __builtin_amdgcn_fdot2(W01, d2, acc[5], false);
                acc[5] = fmaf(W2, (float)d3[0], acc[5]);
                acc[6] = __builtin_amdgcn_fdot2(W12, d3, acc[6], false);
                acc[6] = fmaf(W0, (float)d2[1], acc[6]);
                acc[7] = __builtin_amdgcn_fdot2(W01, d3, acc[7], false);
                acc[7] = fmaf(W2, xp, acc[7]);
            }
        }

        half8 outh;
        #pragma unroll
        for (int j = 0; j < 8; j++){
            float t = (e0 + j < EE) ? fast_tanh(acc[j]) : 0.f;
            outh[j] = (_Float16)t;
        }
        if (lok) *(half8*)(od + gro*KP + e0) = outh;
    }
}

// ---------------- fc1: K-split x6, atomic accumulate into h ------------------
// grid (8,5,6), block 256; h must be zeroed before launch
#define CKK 12
__global__ __launch_bounds__(256) void fc1_kernel(const float* __restrict__ res,
                                                  const float* __restrict__ fw,
                                                  float* __restrict__ h){
    __shared__ float Xt[CKK][68];
    __shared__ float Wts[CKK][68];
    int bt = blockIdx.x, jt = blockIdx.y, kz = blockIdx.z;
    int tid = threadIdx.x, tx = tid & 15, ty = tid >> 4;
    int b0l = bt*64, j0 = jt*64, kbase = kz*300;
    float acc[4][4] = {};
    for (int k0 = 0; k0 < 300; k0 += CKK){
        #pragma unroll
        for (int u = 0; u < 3; u++){
            int idx = tid + u*256;
            int a = idx / CKK, k = idx - a*CKK;
            Xt[k][a] = res[(size_t)(b0l+a)*FCIN + kbase + k0 + k];
            int gj = j0 + a;
            Wts[k][a] = (gj < HH) ? fw[(size_t)gj*FCIN + kbase + k0 + k] : 0.f;
        }
        __syncthreads();
        #pragma unroll
        for (int k = 0; k < CKK; k++){
            float xv[4], wv[4];
            #pragma unroll
            for (int r = 0; r < 4; r++) xv[r] = Xt[k][ty*4+r];
            #pragma unroll
            for (int c = 0; c < 4; c++) wv[c] = Wts[k][tx*4+c];
            #pragma unroll
            for (int r = 0; r < 4; r++)
                #pragma unroll
                for (int c = 0; c < 4; c++)
                    acc[r][c] = fmaf(xv[r], wv[c], acc[r][c]);
        }
        __syncthreads();
    }
    #pragma unroll
    for (int r = 0; r < 4; r++){
        int gb = b0l + ty*4 + r;
        #pragma unroll
        for (int c = 0; c < 4; c++){
            int gj = j0 + tx*4 + c;
            if (gj < HH) atomicAdd(&h[(size_t)gb*HH + gj], acc[r][c]);
        }
    }
}

// ---------------- layernorm + relu + fc2 + softmax (+fc1 bias) ---------------
__global__ void head_kernel(const float* __restrict__ h, const float* __restrict__ fb,
                            const float* __restrict__ g,
                            const float* __restrict__ be, const float* __restrict__ f2w,
                            const float* __restrict__ f2b, float* __restrict__ out){
    int b = blockIdx.x, tid = threadIdx.x;
    __shared__ float arr[HH];
    __shared__ float s_s[4], s_q[4], r0[4], r1[4];
    float x0 = (tid < HH) ? h[(size_t)b*HH + tid] + fb[tid] : 0.f;
    float x1 = (tid + 256 < HH) ? h[(size_t)b*HH + tid + 256] + fb[tid+256] : 0.f;
    float s = x0 + x1, sq = x0*x0 + x1*x1;
    #pragma unroll
    for (int o = 32; o > 0; o >>= 1){ s += __shfl_down(s, o); sq += __shfl_down(sq, o); }
    int wv = tid >> 6, ln = tid & 63;
    if (ln == 0){ s_s[wv] = s; s_q[wv] = sq; }
    __syncthreads();
    s  = s_s[0] + s_s[1] + s_s[2] + s_s[3];
    sq = s_q[0] + s_q[1] + s_q[2] + s_q[3];
    float mean = s / HH;
    float var = sq / HH - mean*mean;
    float inv = rsqrtf(var + 1e-5f);
    if (tid < HH)       arr[tid]     = fmaxf((x0 - mean)*inv*g[tid]     + be[tid],     0.f);
    if (tid + 256 < HH) arr[tid+256] = fmaxf((x1 - mean)*inv*g[tid+256] + be[tid+256], 0.f);
    __syncthreads();
    float p0 = 0.f, p1 = 0.f;
    for (int j = tid; j < HH; j += 256){ float hv = arr[j]; p0 += hv*f2w[j]; p1 += hv*f2w[HH+j]; }
    #pragma unroll
    for (int o = 32; o > 0; o >>= 1){ p0 += __shfl_down(p0, o); p1 += __shfl_down(p1, o); }
    if (ln == 0){ r0[wv] = p0; r1[wv] = p1; }
    __syncthreads();
    if (tid == 0){
        float o0 = r0[0]+r0[1]+r0[2]+r0[3] + f2b[0];
        float o1 = r1[0]+r1[1]+r1[2]+r1[3] + f2b[1];
        out[b*2+0] = o0; out[b*2+1] = o1;
        float m = fmaxf(o0, o1);
        float e0 = __expf(o0 - m), e1 = __expf(o1 - m);
        float den = e0 + e1;
        out[BB*2 + b*2+0] = e0/den;
        out[BB*2 + b*2+1] = e1/den;
    }
}

extern "C" void kernel_launch(void* const* d_in, const int* in_sizes, int n_in,
                              void* d_out, int out_size, void* d_ws, size_t ws_size,
                              hipStream_t stream){
    const int*   seq1   = (const int*)d_in[0];
    const int*   seq2   = (const int*)d_in[1];
    const float* emb    = (const float*)d_in[2];
    const float* W      = (const float*)d_in[3];
    const float* conv_w = (const float*)d_in[4];
    const float* conv_b = (const float*)d_in[5];
    const float* fc1_w  = (const float*)d_in[6];
    const float* fc1_b  = (const float*)d_in[7];
    const float* ln_g   = (const float*)d_in[8];
    const float* ln_b   = (const float*)d_in[9];
    const float* fc2_w  = (const float*)d_in[10];
    const float* fc2_b  = (const float*)d_in[11];
    float* out = (float*)d_out;

    float* ws = (float*)d_ws;
    size_t fixedf = (size_t)BB*FCIN + (size_t)BB*HH + (size_t)KP*SS + 64;
    // per-batch floats: sf16 + o16 (each 2*SS*KP halves) + Ab + AbT + 2 vecs
    size_t perb = (size_t)2*SS*KP + (size_t)(SS*SS) + 2*SS;
    size_t avail = ws_size / 4;
    long long bcl = (long long)((avail > fixedf ? avail - fixedf : 0) / perb);
    int BC = (int)(bcl < 1 ? 1 : (bcl > BB ? BB : bcl));

    float* res = ws;
    float* hb  = res + (size_t)BB*FCIN;
    _Float16* Wt = (_Float16*)(hb + (size_t)BB*HH);
    float* pwt = (float*)(Wt + (size_t)2*KP*SS);
    _Float16* sf1 = (_Float16*)(pwt + 64);
    _Float16* sf2 = sf1 + (size_t)BC*SS*KP;
    _Float16* o16_1 = sf2 + (size_t)BC*SS*KP;
    _Float16* o16_2 = o16_1 + (size_t)BC*SS*KP;
    _Float16* Ab  = o16_2 + (size_t)BC*SS*KP;
    _Float16* AbT = Ab + (size_t)BC*SS*SS;
    float* v1  = (float*)(AbT + (size_t)BC*SS*SS);
    float* v2  = v1 + (size_t)BC*SS;

    wt_build_kernel<<<(2*KP*SS + 255)/256, 256, 0, stream>>>(W, Wt);
    cwpack_kernel<<<1, 64, 0, stream>>>(conv_w, conv_b, pwt);
    hipMemsetAsync(hb, 0, (size_t)BB*HH*sizeof(float), stream);
    hipMemsetAsync(res, 0, (size_t)BB*FCIN*sizeof(float), stream);

    for (int b0 = 0; b0 < BB; b0 += BC){
        int bc = (BB - b0 < BC) ? (BB - b0) : BC;
        embed_kernel<<<dim3(bc, 32, 2), 256, 0, stream>>>(seq1, seq2, emb, sf1, sf2,
                                                          v1, v2, res, b0);
        for (int it = 0; it < LLI; it++){
            cross_matchA<<<bc, 512, 0, stream>>>(sf1, sf2, v1, v2, Ab, AbT);
            f_conv_kernel<<<dim3(bc, 4, 2), 256, 0, stream>>>(Ab, AbT, Wt + (size_t)it*KP*SS,
                                                              sf1, sf2, pwt + it*32,
                                                              o16_1, o16_2);
            mean16_kernel<<<dim3(bc, 2), 320, 0, stream>>>(o16_1, o16_2, res, b0, it+1);
            cross_sums_pool<<<bc, 512, 0, stream>>>(o16_1, o16_2, v1, v2, sf1, sf2);
        }
    }
    fc1_kernel<<<dim3(8, 5, 6), 256, 0, stream>>>(res, fc1_w, hb);
    head_kernel<<<BB, 256, 0, stream>>>(hb, fc1_b, ln_g, ln_b, fc2_w, fc2_b, out);
}

// Round 7
// 769.184 us; speedup vs baseline: 1.1859x; 1.0629x over previous
//
#include <hip/hip_runtime.h>
#include <math.h>

#define BB 512
#define SS 128
#define EE 300
#define HH 300
#define FCIN 1800
#define LLI 2
#define KP 320          // padded K / leading dim for fp16 tensors

using half8 = __attribute__((ext_vector_type(8))) _Float16;
using h2    = __attribute__((ext_vector_type(2))) _Float16;
using f32x4 = __attribute__((ext_vector_type(4))) float;

__device__ __forceinline__ float fast_tanh(float x){
    float ax = fabsf(x);
    float t = __expf(-2.f*ax);
    float r = (1.f - t) * __builtin_amdgcn_rcpf(1.f + t);
    return copysignf(r, x);
}

// 1/(1+sqrt(max(x,0))) with HW approx ops (err ~1e-7 << 7.8e-3 tolerance)
__device__ __forceinline__ float inv1p_sqrt(float x){
    float d = __builtin_amdgcn_sqrtf(fmaxf(x, 0.f));
    return __builtin_amdgcn_rcpf(1.f + d);
}

// norm accumulate of a half8 via 4 fdot2 (constant-index pair extraction)
__device__ __forceinline__ float norm8(half8 hv, float n){
    h2 p0 = __builtin_shufflevector(hv, hv, 0, 1);
    h2 p1 = __builtin_shufflevector(hv, hv, 2, 3);
    h2 p2 = __builtin_shufflevector(hv, hv, 4, 5);
    h2 p3 = __builtin_shufflevector(hv, hv, 6, 7);
    n = __builtin_amdgcn_fdot2(p0, p0, n, false);
    n = __builtin_amdgcn_fdot2(p1, p1, n, false);
    n = __builtin_amdgcn_fdot2(p2, p2, n, false);
    n = __builtin_amdgcn_fdot2(p3, p3, n, false);
    return n;
}

// one conv row-tap: acc[0..7] += W0*left + (W1,W2)-dot2 pattern over d0..d3
__device__ __forceinline__ void conv_row(float* acc, h2 W01, h2 W12, float W0, float W2,
                                         h2 d0, h2 d1, h2 d2, h2 d3, float xm, float xp){
    acc[0] = fmaf(W0, xm,            __builtin_amdgcn_fdot2(W12, d0, acc[0], false));
    acc[1] = fmaf(W2, (float)d1[0],  __builtin_amdgcn_fdot2(W01, d0, acc[1], false));
    acc[2] = fmaf(W0, (float)d0[1],  __builtin_amdgcn_fdot2(W12, d1, acc[2], false));
    acc[3] = fmaf(W2, (float)d2[0],  __builtin_amdgcn_fdot2(W01, d1, acc[3], false));
    acc[4] = fmaf(W0, (float)d1[1],  __builtin_amdgcn_fdot2(W12, d2, acc[4], false));
    acc[5] = fmaf(W2, (float)d3[0],  __builtin_amdgcn_fdot2(W01, d2, acc[5], false));
    acc[6] = fmaf(W0, (float)d2[1],  __builtin_amdgcn_fdot2(W12, d3, acc[6], false));
    acc[7] = fmaf(W2, xp,            __builtin_amdgcn_fdot2(W01, d3, acc[7], false));
}

// ---------------- Wt build: Wt[it][e][j] = W[it][j][e], fp16, e zero-padded to 320
__global__ void wt_build_kernel(const float* __restrict__ W, _Float16* __restrict__ Wt){
    int idx = blockIdx.x*256 + threadIdx.x;      // 2*320*128 = 81920
    if (idx >= 2*KP*SS) return;
    int j = idx & 127;
    int e = (idx >> 7) % KP;
    int it = idx / (KP*SS);
    float v = (e < EE) ? W[(size_t)it*SS*EE + j*EE + e] : 0.f;
    Wt[idx] = (_Float16)v;
}

// ---------------- pack conv weights: per it, 32 dwords:
// [0..5] h2(w0,w1) per (c,dy); [6..11] h2(w1,w2); [12..17] f32 w0; [18..23] f32 w2; [24] bias
__global__ void cwpack_kernel(const float* __restrict__ cw, const float* __restrict__ cb,
                              float* __restrict__ pwt){
    int t = threadIdx.x;
    if (t < 12){
        int it = t / 6, rem = t % 6;          // rem = c*3+dy
        const float* w = cw + it*18 + rem*3;
        float a = w[0], b = w[1], d = w[2];
        h2 p01 = { (_Float16)a, (_Float16)b };
        h2 p12 = { (_Float16)b, (_Float16)d };
        float* o = pwt + it*32;
        ((unsigned*)o)[rem]   = __builtin_bit_cast(unsigned, p01);
        ((unsigned*)o)[6+rem] = __builtin_bit_cast(unsigned, p12);
        o[12+rem] = a;
        o[18+rem] = d;
    }
    if (t < 2) pwt[t*32+24] = cb[t];
}

// ---------------- embed: gather -> sf16 + valid mask + fused seg-0 mean ------
// grid (bc, 32, 2), block 256 (4 waves, wave = 1 row); res must be zeroed
__global__ __launch_bounds__(256) void embed_kernel(
    const int* __restrict__ seq1, const int* __restrict__ seq2,
    const float* __restrict__ emb,
    _Float16* __restrict__ sf1, _Float16* __restrict__ sf2,
    float* __restrict__ v1, float* __restrict__ v2,
    float* __restrict__ res, int b0){
    __shared__ float mred[4][320];
    int bl = blockIdx.x, which = blockIdx.z;
    int w = threadIdx.x >> 6;
    int r = blockIdx.y*4 + w;
    int l = threadIdx.x & 63;
    const int* seq = which ? seq2 : seq1;
    _Float16* sfg = (which ? sf2 : sf1) + (size_t)bl*SS*KP;
    float* vd = (which ? v2 : v1) + bl*SS;
    int token = seq[(size_t)(b0+bl)*SS + r];
    if (l == 0) vd[r] = (token != 0) ? 1.f : 0.f;
    const float* er = emb + (size_t)token * EE;
    int e0 = l*8;
    float x[8];
    if (l < 37){
        float4 a = *(const float4*)(er + e0);
        float4 b = *(const float4*)(er + e0 + 4);
        x[0]=a.x; x[1]=a.y; x[2]=a.z; x[3]=a.w;
        x[4]=b.x; x[5]=b.y; x[6]=b.z; x[7]=b.w;
    } else if (l == 37){
        x[0]=er[296]; x[1]=er[297]; x[2]=er[298]; x[3]=er[299];
        x[4]=0.f; x[5]=0.f; x[6]=0.f; x[7]=0.f;
    } else {
        #pragma unroll
        for (int j = 0; j < 8; j++) x[j] = 0.f;
    }
    if (l < 40){
        half8 hv;
        #pragma unroll
        for (int j = 0; j < 8; j++) hv[j] = (_Float16)x[j];
        *(half8*)(sfg + r*KP + e0) = hv;
        #pragma unroll
        for (int j = 0; j < 8; j++) mred[w][e0 + j] = x[j];
    }
    __syncthreads();
    for (int e = threadIdx.x; e < EE; e += 256){
        float s = mred[0][e] + mred[1][e] + mred[2][e] + mred[3][e];
        atomicAdd(&res[(size_t)(b0+bl)*FCIN + which*900 + e], s * (1.f/SS));
    }
}

// ---------------- MFMA match (A-producing): stages sf16*v, self-computes norms
// block 512 (8 waves); wave = 16 rows x 128 cols. Writes Ab AND AbT (so the
// downstream f kernel reads both A and A^T row-major, no LDS transpose).
__global__ __launch_bounds__(512, 4) void cross_matchA(
    const _Float16* __restrict__ sfA, const _Float16* __restrict__ sfB,
    const float* __restrict__ vAg, const float* __restrict__ vBg,
    _Float16* __restrict__ Ab16, _Float16* __restrict__ AbT16)
{
    __shared__ _Float16 As[128][40];
    __shared__ _Float16 Bs[128][40];
    __shared__ float nAl[128], nBl[128], vAl[128], vBl[128];

    int bl = blockIdx.x;
    int tid = threadIdx.x;
    int w = tid >> 6, lane = tid & 63;
    int m = lane & 15, quad = lane >> 4;

    const _Float16* gA = sfA + (size_t)bl*SS*KP;
    const _Float16* gB = sfB + (size_t)bl*SS*KP;

    if (tid < 128){ vAl[tid] = vAg[bl*SS + tid]; }
    else if (tid < 256){ vBl[tid-128] = vBg[bl*SS + tid-128]; }

    f32x4 acc[8];
    #pragma unroll
    for (int c = 0; c < 8; c++) acc[c] = (f32x4){0.f,0.f,0.f,0.f};

    int srow = tid >> 2, skq = (tid & 3) * 8;
    int arow = w*16 + m;
    float nA = 0.f, nB = 0.f;

    for (int kc = 0; kc < 10; kc++){
        __syncthreads();
        {
            half8 ha = *(const half8*)(gA + srow*KP + kc*32 + skq);
            half8 hb = *(const half8*)(gB + srow*KP + kc*32 + skq);
            ha = ha * (_Float16)vAl[srow];
            hb = hb * (_Float16)vBl[srow];
            *(half8*)&As[srow][skq] = ha;
            *(half8*)&Bs[srow][skq] = hb;
            nA = norm8(ha, nA);
            nB = norm8(hb, nB);
        }
        __syncthreads();
        half8 a = *(const half8*)&As[arow][quad*8];
        #pragma unroll
        for (int c = 0; c < 8; c++){
            half8 b = *(const half8*)&Bs[c*16 + m][quad*8];
            acc[c] = __builtin_amdgcn_mfma_f32_16x16x32_f16(a, b, acc[c], 0, 0, 0);
        }
    }

    nA += __shfl_xor(nA, 1); nA += __shfl_xor(nA, 2);
    nB += __shfl_xor(nB, 1); nB += __shfl_xor(nB, 2);
    if ((tid & 3) == 0){ nAl[srow] = nA; nBl[srow] = nB; }
    __syncthreads();

    int ibase = w*16 + quad*4;
    _Float16* Ao = Ab16 + (size_t)bl*SS*SS;
    _Float16* AoT = AbT16 + (size_t)bl*SS*SS;
    #pragma unroll
    for (int c = 0; c < 8; c++){
        int j = c*16 + m;
        float nc = nBl[j];
        #pragma unroll
        for (int r = 0; r < 4; r++){
            int i = ibase + r;
            float d2 = nAl[i] + nc - 2.f*acc[c][r];
            _Float16 val = (_Float16)inv1p_sqrt(d2);
            Ao[i*SS + j] = val;
            AoT[j*SS + i] = val;
        }
    }
}

// ---------------- MFMA match sums + fused pool/residual (norms self-computed)
// block 512; after w1/w2 (LDS), parallel epilogue: sf += avg3(o*w)
__global__ __launch_bounds__(512, 4) void cross_sums_pool(
    const _Float16* __restrict__ oA, const _Float16* __restrict__ oB,
    const float* __restrict__ vAg, const float* __restrict__ vBg,
    _Float16* __restrict__ sf1, _Float16* __restrict__ sf2)
{
    __shared__ _Float16 As[128][40];
    __shared__ _Float16 Bs[128][40];
    __shared__ float nAl[128], nBl[128], vAl[128], vBl[128];
    __shared__ float colred[8][132];
    __shared__ float wr[128], wc[128];

    int bl = blockIdx.x;
    int tid = threadIdx.x;
    int w = tid >> 6, lane = tid & 63;
    int m = lane & 15, quad = lane >> 4;

    const _Float16* gA = oA + (size_t)bl*SS*KP;
    const _Float16* gB = oB + (size_t)bl*SS*KP;

    if (tid < 128){ vAl[tid] = vAg[bl*SS + tid]; }
    else if (tid < 256){ vBl[tid-128] = vBg[bl*SS + tid-128]; }

    f32x4 acc[8];
    #pragma unroll
    for (int c = 0; c < 8; c++) acc[c] = (f32x4){0.f,0.f,0.f,0.f};

    int srow = tid >> 2, skq = (tid & 3) * 8;
    int arow = w*16 + m;
    float nA = 0.f, nB = 0.f;

    for (int kc = 0; kc < 10; kc++){
        __syncthreads();
        {
            half8 ha = *(const half8*)(gA + srow*KP + kc*32 + skq);
            half8 hb = *(const half8*)(gB + srow*KP + kc*32 + skq);
            ha = ha * (_Float16)vAl[srow];
            hb = hb * (_Float16)vBl[srow];
            *(half8*)&As[srow][skq] = ha;
            *(half8*)&Bs[srow][skq] = hb;
            nA = norm8(ha, nA);
            nB = norm8(hb, nB);
        }
        __syncthreads();
        half8 a = *(const half8*)&As[arow][quad*8];
        #pragma unroll
        for (int c = 0; c < 8; c++){
            half8 b = *(const half8*)&Bs[c*16 + m][quad*8];
            acc[c] = __builtin_amdgcn_mfma_f32_16x16x32_f16(a, b, acc[c], 0, 0, 0);
        }
    }

    nA += __shfl_xor(nA, 1); nA += __shfl_xor(nA, 2);
    nB += __shfl_xor(nB, 1); nB += __shfl_xor(nB, 2);
    if ((tid & 3) == 0){ nAl[srow] = nA; nBl[srow] = nB; }
    __syncthreads();

    int ibase = w*16 + quad*4;
    float aval[8][4];
    #pragma unroll
    for (int c = 0; c < 8; c++){
        float nc = nBl[c*16 + m];
        #pragma unroll
        for (int r = 0; r < 4; r++){
            float d2 = nAl[ibase+r] + nc - 2.f*acc[c][r];
            aval[c][r] = inv1p_sqrt(d2);
        }
    }

    // row sums -> wr
    float rp[4];
    #pragma unroll
    for (int r = 0; r < 4; r++){
        float s = 0.f;
        #pragma unroll
        for (int c = 0; c < 8; c++) s += aval[c][r];
        rp[r] = s;
    }
    #pragma unroll
    for (int mask = 1; mask < 16; mask <<= 1)
        #pragma unroll
        for (int r = 0; r < 4; r++) rp[r] += __shfl_xor(rp[r], mask);
    if (m == 0){
        #pragma unroll
        for (int r = 0; r < 4; r++) wr[ibase + r] = rp[r];
    }
    // col sums -> wc
    float cp[8];
    #pragma unroll
    for (int c = 0; c < 8; c++){
        float s = 0.f;
        #pragma unroll
        for (int r = 0; r < 4; r++) s += aval[c][r];
        cp[c] = s;
    }
    #pragma unroll
    for (int c = 0; c < 8; c++){
        cp[c] += __shfl_xor(cp[c], 16);
        cp[c] += __shfl_xor(cp[c], 32);
    }
    if (quad == 0){
        #pragma unroll
        for (int c = 0; c < 8; c++) colred[w][c*16 + m] = cp[c];
    }
    __syncthreads();
    if (tid < 128){
        float s = 0.f;
        #pragma unroll
        for (int g = 0; g < 8; g++) s += colred[g][tid];
        wc[tid] = s;
    }
    __syncthreads();

    // ---- fused pool epilogue: 4 lanes per row (tid>>2 = row, tid&3 = sub) ----
    int prow = tid >> 2, sub = tid & 3;
    #pragma unroll
    for (int which = 0; which < 2; which++){
        const _Float16* og = which ? gB : gA;
        const float* wv = which ? wc : wr;
        _Float16* sg = (which ? sf2 : sf1) + (size_t)bl*SS*KP;
        float w0 = wv[prow];
        float wm = (prow > 0)   ? wv[prow-1] : 0.f;
        float wp = (prow < 127) ? wv[prow+1] : 0.f;
        #pragma unroll
        for (int k = 0; k < 10; k++){
            int e0 = (sub + k*4) * 8;           // < 320
            half8 o0 = *(const half8*)(og + prow*KP + e0);
            half8 om = {};
            half8 op = {};
            if (prow > 0)   om = *(const half8*)(og + (prow-1)*KP + e0);
            if (prow < 127) op = *(const half8*)(og + (prow+1)*KP + e0);
            half8 sv = *(const half8*)(sg + prow*KP + e0);
            half8 outh;
            #pragma unroll
            for (int j = 0; j < 8; j++){
                float a = (float)o0[j]*w0 + (float)om[j]*wm + (float)op[j]*wp;
                float ns = (float)sv[j] + a * (1.f/3.f);
                outh[j] = (_Float16)ns;
            }
            *(half8*)(sg + prow*KP + e0) = outh;
        }
    }
}

// ---------------- fused f = A@W (zz=0) / A^T@W (zz=1, from AbT) -> LDS -------
// -> conv3x3 + tanh -> o16 + fused column-mean (atomicAdd into res).
// grid (bc, 4 row-strips, 2), block 256 (4 waves). Strip rs covers output rows
// [rs*32, rs*32+32); ftile holds f rows [rs*32-8, rs*32+40) (OOB zeroed).
// Phase 2: wave=row-PAIR conv: 2 output rows share a 4-row input window ->
// 33% fewer loads, 2 independent acc chains (ILP). Full-row coalesced stores.
__global__ __launch_bounds__(256, 5) void f_conv_kernel(
    const _Float16* __restrict__ Ab, const _Float16* __restrict__ AbT,
    const _Float16* __restrict__ Wt,
    const _Float16* __restrict__ sf1, const _Float16* __restrict__ sf2,
    const float* __restrict__ pw,
    _Float16* __restrict__ o16_1, _Float16* __restrict__ o16_2,
    float* __restrict__ res, int b0, int seg)
{
    __shared__ _Float16 ftile[48][328];          // +8 pad: de-conflict phase-1 writes

    int bl = blockIdx.x, rs = blockIdx.y, zz = blockIdx.z;
    int R0 = rs*32 - 8;
    int tid = threadIdx.x, w = tid >> 6, lane = tid & 63;
    int m = lane & 15, quad = lane >> 4;

    // conv weights (uniform loads)
    const unsigned* pu = (const unsigned*)pw;
    h2 w01[2][3], w12[2][3];
    float w0f[2][3], w2f[2][3];
    #pragma unroll
    for (int c = 0; c < 2; c++)
        #pragma unroll
        for (int dy = 0; dy < 3; dy++){
            int rem = c*3 + dy;
            w01[c][dy] = __builtin_bit_cast(h2, pu[rem]);
            w12[c][dy] = __builtin_bit_cast(h2, pu[6 + rem]);
            w0f[c][dy] = pw[12 + rem];
            w2f[c][dy] = pw[18 + rem];
        }
    float bias = pw[24];

    // ---- phase 1: f rows [R0, R0+48) x cols 0..303 via MFMA ----
    const _Float16* gA = (zz ? AbT : Ab) + (size_t)bl*SS*SS;
    #pragma unroll
    for (int rg = 0; rg < 3; rg++){
        int gar = R0 + rg*16 + m;                      // A row for this lane
        int gac = gar < 0 ? 0 : (gar > SS-1 ? SS-1 : gar);   // clamp (OOB rows zeroed below)
        half8 a[4];
        #pragma unroll
        for (int kc = 0; kc < 4; kc++)
            a[kc] = *(const half8*)(gA + gac*SS + kc*32 + quad*8);
        #pragma unroll
        for (int ci = 0; ci < 5; ci++){
            int c = w + ci*4;                          // wave-strided col frags
            if (c < 19){
                int e = c*16 + m;                      // 0..303
                f32x4 acc = (f32x4){0.f,0.f,0.f,0.f};
                #pragma unroll
                for (int kc = 0; kc < 4; kc++){
                    half8 b = *(const half8*)(Wt + (size_t)e*SS + kc*32 + quad*8);
                    acc = __builtin_amdgcn_mfma_f32_16x16x32_f16(a[kc], b, acc, 0, 0, 0);
                }
                #pragma unroll
                for (int r = 0; r < 4; r++){
                    int lr = rg*16 + quad*4 + r;
                    int gf = R0 + lr;
                    bool ok = (gf >= 0) && (gf < SS) && (e < EE);
                    ftile[lr][e] = ok ? (_Float16)acc[r] : (_Float16)0.f;
                }
            }
        }
    }
    // zero-fill cols 304..319 (uniform padding for conv)
    for (int idx = tid; idx < 48*16; idx += 256)
        ftile[idx >> 4][304 + (idx & 15)] = (_Float16)0.f;
    __syncthreads();

    // ---- phase 2: conv(3x3, ch0=sf global, ch1=f LDS) + tanh -> o16 ----
    const _Float16* cs = (zz ? sf2 : sf1) + (size_t)bl*SS*KP;
    _Float16* od = (zz ? o16_2 : o16_1) + (size_t)bl*SS*KP;
    int l = lane, e0 = l*8;
    bool lok = (l < 40);
    float msum[8];
    #pragma unroll
    for (int j = 0; j < 8; j++) msum[j] = 0.f;

    for (int p = 0; p < 4; p++){
        int roA = rs*32 + w*8 + 2*p;            // output rows roA, roA+1
        int lrA = w*8 + 2*p + 8;                // ftile local row of roA
        float accA[8], accB[8];
        #pragma unroll
        for (int j = 0; j < 8; j++){ accA[j] = bias; accB[j] = bias; }

        #pragma unroll
        for (int c = 0; c < 2; c++){
            #pragma unroll
            for (int q = 0; q < 4; q++){        // input row = roA - 1 + q
                half8 hv = {};
                if (c == 0){
                    int gr = roA - 1 + q;
                    if (gr >= 0 && gr < SS && lok)
                        hv = *(const half8*)(cs + gr*KP + e0);
                } else {
                    if (lok) hv = *(const half8*)&ftile[lrA - 1 + q][e0];
                }
                h2 d0 = __builtin_shufflevector(hv, hv, 0, 1);
                h2 d1 = __builtin_shufflevector(hv, hv, 2, 3);
                h2 d2 = __builtin_shufflevector(hv, hv, 4, 5);
                h2 d3 = __builtin_shufflevector(hv, hv, 6, 7);
                int dmi = __shfl_up(__builtin_bit_cast(int, d3), 1);
                int dpi = __shfl_down(__builtin_bit_cast(int, d0), 1);
                h2 dmh = __builtin_bit_cast(h2, dmi);
                h2 dph = __builtin_bit_cast(h2, dpi);
                float xm = (l == 0) ? 0.f : (float)dmh[1];
                float xp = (float)dph[0];
                if (q <= 2)
                    conv_row(accA, w01[c][q], w12[c][q], w0f[c][q], w2f[c][q],
                             d0, d1, d2, d3, xm, xp);
                if (q >= 1)
                    conv_row(accB, w01[c][q-1], w12[c][q-1], w0f[c][q-1], w2f[c][q-1],
                             d0, d1, d2, d3, xm, xp);
            }
        }

        half8 outA, outB;
        #pragma unroll
        for (int j = 0; j < 8; j++){
            bool ev = (e0 + j < EE);
            float tA = ev ? fast_tanh(accA[j]) : 0.f;
            float tB = ev ? fast_tanh(accB[j]) : 0.f;
            outA[j] = (_Float16)tA;
            outB[j] = (_Float16)tB;
            msum[j] += tA + tB;
        }
        if (lok){
            *(half8*)(od + roA*KP + e0) = outA;
            *(half8*)(od + (roA+1)*KP + e0) = outB;
        }
    }

    // ---- fused column-mean: LDS partial over 4 waves, atomicAdd into res ----
    __syncthreads();                             // all ftile reads done
    float* mred = (float*)&ftile[0][0];          // alias: [4][320] floats
    if (lok){
        #pragma unroll
        for (int j = 0; j < 8; j++) mred[w*320 + e0 + j] = msum[j];
    }
    __syncthreads();
    for (int e = tid; e < EE; e += 256){
        float s = mred[e] + mred[320+e] + mred[640+e] + mred[960+e];
        atomicAdd(&res[(size_t)(b0+bl)*FCIN + zz*900 + seg*300 + e], s * (1.f/SS));
    }
}

// ---------------- fc1: K-split x6, atomic accumulate into h ------------------
// grid (8,5,6), block 256; h must be zeroed before launch
#define CKK 12
__global__ __launch_bounds__(256) void fc1_kernel(const float* __restrict__ res,
                                                  const float* __restrict__ fw,
                                                  float* __restrict__ h){
    __shared__ float Xt[CKK][68];
    __shared__ float Wts[CKK][68];
    int bt = blockIdx.x, jt = blockIdx.y, kz = blockIdx.z;
    int tid = threadIdx.x, tx = tid & 15, ty = tid >> 4;
    int b0l = bt*64, j0 = jt*64, kbase = kz*300;
    float acc[4][4] = {};
    for (int k0 = 0; k0 < 300; k0 += CKK){
        #pragma unroll
        for (int u = 0; u < 3; u++){
            int idx = tid + u*256;
            int a = idx / CKK, k = idx - a*CKK;
            Xt[k][a] = res[(size_t)(b0l+a)*FCIN + kbase + k0 + k];
            int gj = j0 + a;
            Wts[k][a] = (gj < HH) ? fw[(size_t)gj*FCIN + kbase + k0 + k] : 0.f;
        }
        __syncthreads();
        #pragma unroll
        for (int k = 0; k < CKK; k++){
            float xv[4], wv[4];
            #pragma unroll
            for (int r = 0; r < 4; r++) xv[r] = Xt[k][ty*4+r];
            #pragma unroll
            for (int c = 0; c < 4; c++) wv[c] = Wts[k][tx*4+c];
            #pragma unroll
            for (int r = 0; r < 4; r++)
                #pragma unroll
                for (int c = 0; c < 4; c++)
                    acc[r][c] = fmaf(xv[r], wv[c], acc[r][c]);
        }
        __syncthreads();
    }
    #pragma unroll
    for (int r = 0; r < 4; r++){
        int gb = b0l + ty*4 + r;
        #pragma unroll
        for (int c = 0; c < 4; c++){
            int gj = j0 + tx*4 + c;
            if (gj < HH) atomicAdd(&h[(size_t)gb*HH + gj], acc[r][c]);
        }
    }
}

// ---------------- layernorm + relu + fc2 + softmax (+fc1 bias) ---------------
__global__ void head_kernel(const float* __restrict__ h, const float* __restrict__ fb,
                            const float* __restrict__ g,
                            const float* __restrict__ be, const float* __restrict__ f2w,
                            const float* __restrict__ f2b, float* __restrict__ out){
    int b = blockIdx.x, tid = threadIdx.x;
    __shared__ float arr[HH];
    __shared__ float s_s[4], s_q[4], r0[4], r1[4];
    float x0 = (tid < HH) ? h[(size_t)b*HH + tid] + fb[tid] : 0.f;
    float x1 = (tid + 256 < HH) ? h[(size_t)b*HH + tid + 256] + fb[tid+256] : 0.f;
    float s = x0 + x1, sq = x0*x0 + x1*x1;
    #pragma unroll
    for (int o = 32; o > 0; o >>= 1){ s += __shfl_down(s, o); sq += __shfl_down(sq, o); }
    int wv = tid >> 6, ln = tid & 63;
    if (ln == 0){ s_s[wv] = s; s_q[wv] = sq; }
    __syncthreads();
    s  = s_s[0] + s_s[1] + s_s[2] + s_s[3];
    sq = s_q[0] + s_q[1] + s_q[2] + s_q[3];
    float mean = s / HH;
    float var = sq / HH - mean*mean;
    float inv = rsqrtf(var + 1e-5f);
    if (tid < HH)       arr[tid]     = fmaxf((x0 - mean)*inv*g[tid]     + be[tid],     0.f);
    if (tid + 256 < HH) arr[tid+256] = fmaxf((x1 - mean)*inv*g[tid+256] + be[tid+256], 0.f);
    __syncthreads();
    float p0 = 0.f, p1 = 0.f;
    for (int j = tid; j < HH; j += 256){ float hv = arr[j]; p0 += hv*f2w[j]; p1 += hv*f2w[HH+j]; }
    #pragma unroll
    for (int o = 32; o > 0; o >>= 1){ p0 += __shfl_down(p0, o); p1 += __shfl_down(p1, o); }
    if (ln == 0){ r0[wv] = p0; r1[wv] = p1; }
    __syncthreads();
    if (tid == 0){
        float o0 = r0[0]+r0[1]+r0[2]+r0[3] + f2b[0];
        float o1 = r1[0]+r1[1]+r1[2]+r1[3] + f2b[1];
        out[b*2+0] = o0; out[b*2+1] = o1;
        float m = fmaxf(o0, o1);
        float e0 = __expf(o0 - m), e1 = __expf(o1 - m);
        float den = e0 + e1;
        out[BB*2 + b*2+0] = e0/den;
        out[BB*2 + b*2+1] = e1/den;
    }
}

extern "C" void kernel_launch(void* const* d_in, const int* in_sizes, int n_in,
                              void* d_out, int out_size, void* d_ws, size_t ws_size,
                              hipStream_t stream){
    const int*   seq1   = (const int*)d_in[0];
    const int*   seq2   = (const int*)d_in[1];
    const float* emb    = (const float*)d_in[2];
    const float* W      = (const float*)d_in[3];
    const float* conv_w = (const float*)d_in[4];
    const float* conv_b = (const float*)d_in[5];
    const float* fc1_w  = (const float*)d_in[6];
    const float* fc1_b  = (const float*)d_in[7];
    const float* ln_g   = (const float*)d_in[8];
    const float* ln_b   = (const float*)d_in[9];
    const float* fc2_w  = (const float*)d_in[10];
    const float* fc2_b  = (const float*)d_in[11];
    float* out = (float*)d_out;

    float* ws = (float*)d_ws;
    size_t fixedf = (size_t)BB*FCIN + (size_t)BB*HH + (size_t)KP*SS + 64;
    // per-batch floats: sf16 + o16 (each 2*SS*KP halves) + Ab + AbT + 2 vecs
    size_t perb = (size_t)2*SS*KP + (size_t)(SS*SS) + 2*SS;
    size_t avail = ws_size / 4;
    long long bcl = (long long)((avail > fixedf ? avail - fixedf : 0) / perb);
    int BC = (int)(bcl < 1 ? 1 : (bcl > BB ? BB : bcl));

    float* res = ws;
    float* hb  = res + (size_t)BB*FCIN;
    _Float16* Wt = (_Float16*)(hb + (size_t)BB*HH);
    float* pwt = (float*)(Wt + (size_t)2*KP*SS);
    _Float16* sf1 = (_Float16*)(pwt + 64);
    _Float16* sf2 = sf1 + (size_t)BC*SS*KP;
    _Float16* o16_1 = sf2 + (size_t)BC*SS*KP;
    _Float16* o16_2 = o16_1 + (size_t)BC*SS*KP;
    _Float16* Ab  = o16_2 + (size_t)BC*SS*KP;
    _Float16* AbT = Ab + (size_t)BC*SS*SS;
    float* v1  = (float*)(AbT + (size_t)BC*SS*SS);
    float* v2  = v1 + (size_t)BC*SS;

    wt_build_kernel<<<(2*KP*SS + 255)/256, 256, 0, stream>>>(W, Wt);
    cwpack_kernel<<<1, 64, 0, stream>>>(conv_w, conv_b, pwt);
    hipMemsetAsync(hb, 0, (size_t)BB*HH*sizeof(float), stream);
    hipMemsetAsync(res, 0, (size_t)BB*FCIN*sizeof(float), stream);

    for (int b0 = 0; b0 < BB; b0 += BC){
        int bc = (BB - b0 < BC) ? (BB - b0) : BC;
        embed_kernel<<<dim3(bc, 32, 2), 256, 0, stream>>>(seq1, seq2, emb, sf1, sf2,
                                                          v1, v2, res, b0);
        for (int it = 0; it < LLI; it++){
            cross_matchA<<<bc, 512, 0, stream>>>(sf1, sf2, v1, v2, Ab, AbT);
            f_conv_kernel<<<dim3(bc, 4, 2), 256, 0, stream>>>(Ab, AbT, Wt + (size_t)it*KP*SS,
                                                              sf1, sf2, pwt + it*32,
                                                              o16_1, o16_2, res, b0, it+1);
            cross_sums_pool<<<bc, 512, 0, stream>>>(o16_1, o16_2, v1, v2, sf1, sf2);
        }
    }
    fc1_kernel<<<dim3(8, 5, 6), 256, 0, stream>>>(res, fc1_w, hb);
    head_kernel<<<BB, 256, 0, stream>>>(hb, fc1_b, ln_g, ln_b, fc2_w, fc2_b, out);
}

// Round 8
// 741.777 us; speedup vs baseline: 1.2297x; 1.0369x over previous
//
#include <hip/hip_runtime.h>
#include <math.h>

#define BB 512
#define SS 128
#define EE 300
#define HH 300
#define FCIN 1800
#define LLI 2
#define KP 320          // padded K / leading dim for fp16 tensors

using half8 = __attribute__((ext_vector_type(8))) _Float16;
using h2    = __attribute__((ext_vector_type(2))) _Float16;
using f32x4 = __attribute__((ext_vector_type(4))) float;

__device__ __forceinline__ float fast_tanh(float x){
    float ax = fabsf(x);
    float t = __expf(-2.f*ax);
    float r = (1.f - t) * __builtin_amdgcn_rcpf(1.f + t);
    return copysignf(r, x);
}

// 1/(1+sqrt(max(x,0))) with HW approx ops (err ~1e-7 << 7.8e-3 tolerance)
__device__ __forceinline__ float inv1p_sqrt(float x){
    float d = __builtin_amdgcn_sqrtf(fmaxf(x, 0.f));
    return __builtin_amdgcn_rcpf(1.f + d);
}

// norm accumulate of a half8 via 4 fdot2 (constant-index pair extraction)
__device__ __forceinline__ float norm8(half8 hv, float n){
    h2 p0 = __builtin_shufflevector(hv, hv, 0, 1);
    h2 p1 = __builtin_shufflevector(hv, hv, 2, 3);
    h2 p2 = __builtin_shufflevector(hv, hv, 4, 5);
    h2 p3 = __builtin_shufflevector(hv, hv, 6, 7);
    n = __builtin_amdgcn_fdot2(p0, p0, n, false);
    n = __builtin_amdgcn_fdot2(p1, p1, n, false);
    n = __builtin_amdgcn_fdot2(p2, p2, n, false);
    n = __builtin_amdgcn_fdot2(p3, p3, n, false);
    return n;
}

// one conv row-tap: acc[0..7] += W0*left + (W1,W2)-dot2 pattern over d0..d3
__device__ __forceinline__ void conv_row(float* acc, h2 W01, h2 W12, float W0, float W2,
                                         h2 d0, h2 d1, h2 d2, h2 d3, float xm, float xp){
    acc[0] = fmaf(W0, xm,            __builtin_amdgcn_fdot2(W12, d0, acc[0], false));
    acc[1] = fmaf(W2, (float)d1[0],  __builtin_amdgcn_fdot2(W01, d0, acc[1], false));
    acc[2] = fmaf(W0, (float)d0[1],  __builtin_amdgcn_fdot2(W12, d1, acc[2], false));
    acc[3] = fmaf(W2, (float)d2[0],  __builtin_amdgcn_fdot2(W01, d1, acc[3], false));
    acc[4] = fmaf(W0, (float)d1[1],  __builtin_amdgcn_fdot2(W12, d2, acc[4], false));
    acc[5] = fmaf(W2, (float)d3[0],  __builtin_amdgcn_fdot2(W01, d2, acc[5], false));
    acc[6] = fmaf(W0, (float)d2[1],  __builtin_amdgcn_fdot2(W12, d3, acc[6], false));
    acc[7] = fmaf(W2, xp,            __builtin_amdgcn_fdot2(W01, d3, acc[7], false));
}

// ---------------- Wt build: Wt[it][e][j] = W[it][j][e], fp16, e zero-padded to 320
__global__ void wt_build_kernel(const float* __restrict__ W, _Float16* __restrict__ Wt){
    int idx = blockIdx.x*256 + threadIdx.x;      // 2*320*128 = 81920
    if (idx >= 2*KP*SS) return;
    int j = idx & 127;
    int e = (idx >> 7) % KP;
    int it = idx / (KP*SS);
    float v = (e < EE) ? W[(size_t)it*SS*EE + j*EE + e] : 0.f;
    Wt[idx] = (_Float16)v;
}

// ---------------- pack conv weights: per it, 32 dwords:
// [0..5] h2(w0,w1) per (c,dy); [6..11] h2(w1,w2); [12..17] f32 w0; [18..23] f32 w2; [24] bias
__global__ void cwpack_kernel(const float* __restrict__ cw, const float* __restrict__ cb,
                              float* __restrict__ pwt){
    int t = threadIdx.x;
    if (t < 12){
        int it = t / 6, rem = t % 6;          // rem = c*3+dy
        const float* w = cw + it*18 + rem*3;
        float a = w[0], b = w[1], d = w[2];
        h2 p01 = { (_Float16)a, (_Float16)b };
        h2 p12 = { (_Float16)b, (_Float16)d };
        float* o = pwt + it*32;
        ((unsigned*)o)[rem]   = __builtin_bit_cast(unsigned, p01);
        ((unsigned*)o)[6+rem] = __builtin_bit_cast(unsigned, p12);
        o[12+rem] = a;
        o[18+rem] = d;
    }
    if (t < 2) pwt[t*32+24] = cb[t];
}

// ---------------- embed: gather -> sf16 + valid mask + fused seg-0 mean ------
// grid (bc, 32, 2), block 256 (4 waves, wave = 1 row); res must be zeroed
__global__ __launch_bounds__(256) void embed_kernel(
    const int* __restrict__ seq1, const int* __restrict__ seq2,
    const float* __restrict__ emb,
    _Float16* __restrict__ sf1, _Float16* __restrict__ sf2,
    float* __restrict__ v1, float* __restrict__ v2,
    float* __restrict__ res, int b0){
    __shared__ float mred[4][320];
    int bl = blockIdx.x, which = blockIdx.z;
    int w = threadIdx.x >> 6;
    int r = blockIdx.y*4 + w;
    int l = threadIdx.x & 63;
    const int* seq = which ? seq2 : seq1;
    _Float16* sfg = (which ? sf2 : sf1) + (size_t)bl*SS*KP;
    float* vd = (which ? v2 : v1) + bl*SS;
    int token = seq[(size_t)(b0+bl)*SS + r];
    if (l == 0) vd[r] = (token != 0) ? 1.f : 0.f;
    const float* er = emb + (size_t)token * EE;
    int e0 = l*8;
    float x[8];
    if (l < 37){
        float4 a = *(const float4*)(er + e0);
        float4 b = *(const float4*)(er + e0 + 4);
        x[0]=a.x; x[1]=a.y; x[2]=a.z; x[3]=a.w;
        x[4]=b.x; x[5]=b.y; x[6]=b.z; x[7]=b.w;
    } else if (l == 37){
        x[0]=er[296]; x[1]=er[297]; x[2]=er[298]; x[3]=er[299];
        x[4]=0.f; x[5]=0.f; x[6]=0.f; x[7]=0.f;
    } else {
        #pragma unroll
        for (int j = 0; j < 8; j++) x[j] = 0.f;
    }
    if (l < 40){
        half8 hv;
        #pragma unroll
        for (int j = 0; j < 8; j++) hv[j] = (_Float16)x[j];
        *(half8*)(sfg + r*KP + e0) = hv;
        #pragma unroll
        for (int j = 0; j < 8; j++) mred[w][e0 + j] = x[j];
    }
    __syncthreads();
    for (int e = threadIdx.x; e < EE; e += 256){
        float s = mred[0][e] + mred[1][e] + mred[2][e] + mred[3][e];
        atomicAdd(&res[(size_t)(b0+bl)*FCIN + which*900 + e], s * (1.f/SS));
    }
}

// ---------------- MFMA match (A-producing): stages sf16*v, self-computes norms
// block 512 (8 waves); wave = 16 rows x 128 cols. Writes Ab AND AbT (so the
// downstream f kernel reads both A and A^T row-major, no LDS transpose).
__global__ __launch_bounds__(512, 4) void cross_matchA(
    const _Float16* __restrict__ sfA, const _Float16* __restrict__ sfB,
    const float* __restrict__ vAg, const float* __restrict__ vBg,
    _Float16* __restrict__ Ab16, _Float16* __restrict__ AbT16)
{
    __shared__ _Float16 As[128][40];
    __shared__ _Float16 Bs[128][40];
    __shared__ float nAl[128], nBl[128], vAl[128], vBl[128];

    int bl = blockIdx.x;
    int tid = threadIdx.x;
    int w = tid >> 6, lane = tid & 63;
    int m = lane & 15, quad = lane >> 4;

    const _Float16* gA = sfA + (size_t)bl*SS*KP;
    const _Float16* gB = sfB + (size_t)bl*SS*KP;

    if (tid < 128){ vAl[tid] = vAg[bl*SS + tid]; }
    else if (tid < 256){ vBl[tid-128] = vBg[bl*SS + tid-128]; }

    f32x4 acc[8];
    #pragma unroll
    for (int c = 0; c < 8; c++) acc[c] = (f32x4){0.f,0.f,0.f,0.f};

    int srow = tid >> 2, skq = (tid & 3) * 8;
    int arow = w*16 + m;
    float nA = 0.f, nB = 0.f;

    for (int kc = 0; kc < 10; kc++){
        __syncthreads();
        {
            half8 ha = *(const half8*)(gA + srow*KP + kc*32 + skq);
            half8 hb = *(const half8*)(gB + srow*KP + kc*32 + skq);
            ha = ha * (_Float16)vAl[srow];
            hb = hb * (_Float16)vBl[srow];
            *(half8*)&As[srow][skq] = ha;
            *(half8*)&Bs[srow][skq] = hb;
            nA = norm8(ha, nA);
            nB = norm8(hb, nB);
        }
        __syncthreads();
        half8 a = *(const half8*)&As[arow][quad*8];
        #pragma unroll
        for (int c = 0; c < 8; c++){
            half8 b = *(const half8*)&Bs[c*16 + m][quad*8];
            acc[c] = __builtin_amdgcn_mfma_f32_16x16x32_f16(a, b, acc[c], 0, 0, 0);
        }
    }

    nA += __shfl_xor(nA, 1); nA += __shfl_xor(nA, 2);
    nB += __shfl_xor(nB, 1); nB += __shfl_xor(nB, 2);
    if ((tid & 3) == 0){ nAl[srow] = nA; nBl[srow] = nB; }
    __syncthreads();

    int ibase = w*16 + quad*4;
    _Float16* Ao = Ab16 + (size_t)bl*SS*SS;
    _Float16* AoT = AbT16 + (size_t)bl*SS*SS;
    #pragma unroll
    for (int c = 0; c < 8; c++){
        int j = c*16 + m;
        float nc = nBl[j];
        #pragma unroll
        for (int r = 0; r < 4; r++){
            int i = ibase + r;
            float d2 = nAl[i] + nc - 2.f*acc[c][r];
            _Float16 val = (_Float16)inv1p_sqrt(d2);
            Ao[i*SS + j] = val;
            AoT[j*SS + i] = val;
        }
    }
}

// ---------------- MFMA match sums + fused pool/residual (norms self-computed)
// block 512; after w1/w2 (LDS), parallel epilogue: sf += avg3(o*w)
__global__ __launch_bounds__(512, 4) void cross_sums_pool(
    const _Float16* __restrict__ oA, const _Float16* __restrict__ oB,
    const float* __restrict__ vAg, const float* __restrict__ vBg,
    _Float16* __restrict__ sf1, _Float16* __restrict__ sf2)
{
    __shared__ _Float16 As[128][40];
    __shared__ _Float16 Bs[128][40];
    __shared__ float nAl[128], nBl[128], vAl[128], vBl[128];
    __shared__ float colred[8][132];
    __shared__ float wr[128], wc[128];

    int bl = blockIdx.x;
    int tid = threadIdx.x;
    int w = tid >> 6, lane = tid & 63;
    int m = lane & 15, quad = lane >> 4;

    const _Float16* gA = oA + (size_t)bl*SS*KP;
    const _Float16* gB = oB + (size_t)bl*SS*KP;

    if (tid < 128){ vAl[tid] = vAg[bl*SS + tid]; }
    else if (tid < 256){ vBl[tid-128] = vBg[bl*SS + tid-128]; }

    f32x4 acc[8];
    #pragma unroll
    for (int c = 0; c < 8; c++) acc[c] = (f32x4){0.f,0.f,0.f,0.f};

    int srow = tid >> 2, skq = (tid & 3) * 8;
    int arow = w*16 + m;
    float nA = 0.f, nB = 0.f;

    for (int kc = 0; kc < 10; kc++){
        __syncthreads();
        {
            half8 ha = *(const half8*)(gA + srow*KP + kc*32 + skq);
            half8 hb = *(const half8*)(gB + srow*KP + kc*32 + skq);
            ha = ha * (_Float16)vAl[srow];
            hb = hb * (_Float16)vBl[srow];
            *(half8*)&As[srow][skq] = ha;
            *(half8*)&Bs[srow][skq] = hb;
            nA = norm8(ha, nA);
            nB = norm8(hb, nB);
        }
        __syncthreads();
        half8 a = *(const half8*)&As[arow][quad*8];
        #pragma unroll
        for (int c = 0; c < 8; c++){
            half8 b = *(const half8*)&Bs[c*16 + m][quad*8];
            acc[c] = __builtin_amdgcn_mfma_f32_16x16x32_f16(a, b, acc[c], 0, 0, 0);
        }
    }

    nA += __shfl_xor(nA, 1); nA += __shfl_xor(nA, 2);
    nB += __shfl_xor(nB, 1); nB += __shfl_xor(nB, 2);
    if ((tid & 3) == 0){ nAl[srow] = nA; nBl[srow] = nB; }
    __syncthreads();

    int ibase = w*16 + quad*4;
    float aval[8][4];
    #pragma unroll
    for (int c = 0; c < 8; c++){
        float nc = nBl[c*16 + m];
        #pragma unroll
        for (int r = 0; r < 4; r++){
            float d2 = nAl[ibase+r] + nc - 2.f*acc[c][r];
            aval[c][r] = inv1p_sqrt(d2);
        }
    }

    // row sums -> wr
    float rp[4];
    #pragma unroll
    for (int r = 0; r < 4; r++){
        float s = 0.f;
        #pragma unroll
        for (int c = 0; c < 8; c++) s += aval[c][r];
        rp[r] = s;
    }
    #pragma unroll
    for (int mask = 1; mask < 16; mask <<= 1)
        #pragma unroll
        for (int r = 0; r < 4; r++) rp[r] += __shfl_xor(rp[r], mask);
    if (m == 0){
        #pragma unroll
        for (int r = 0; r < 4; r++) wr[ibase + r] = rp[r];
    }
    // col sums -> wc
    float cp[8];
    #pragma unroll
    for (int c = 0; c < 8; c++){
        float s = 0.f;
        #pragma unroll
        for (int r = 0; r < 4; r++) s += aval[c][r];
        cp[c] = s;
    }
    #pragma unroll
    for (int c = 0; c < 8; c++){
        cp[c] += __shfl_xor(cp[c], 16);
        cp[c] += __shfl_xor(cp[c], 32);
    }
    if (quad == 0){
        #pragma unroll
        for (int c = 0; c < 8; c++) colred[w][c*16 + m] = cp[c];
    }
    __syncthreads();
    if (tid < 128){
        float s = 0.f;
        #pragma unroll
        for (int g = 0; g < 8; g++) s += colred[g][tid];
        wc[tid] = s;
    }
    __syncthreads();

    // ---- fused pool epilogue: 4 lanes per row (tid>>2 = row, tid&3 = sub) ----
    int prow = tid >> 2, sub = tid & 3;
    #pragma unroll
    for (int which = 0; which < 2; which++){
        const _Float16* og = which ? gB : gA;
        const float* wv = which ? wc : wr;
        _Float16* sg = (which ? sf2 : sf1) + (size_t)bl*SS*KP;
        float w0 = wv[prow];
        float wm = (prow > 0)   ? wv[prow-1] : 0.f;
        float wp = (prow < 127) ? wv[prow+1] : 0.f;
        #pragma unroll
        for (int k = 0; k < 10; k++){
            int e0 = (sub + k*4) * 8;           // < 320
            half8 o0 = *(const half8*)(og + prow*KP + e0);
            half8 om = {};
            half8 op = {};
            if (prow > 0)   om = *(const half8*)(og + (prow-1)*KP + e0);
            if (prow < 127) op = *(const half8*)(og + (prow+1)*KP + e0);
            half8 sv = *(const half8*)(sg + prow*KP + e0);
            half8 outh;
            #pragma unroll
            for (int j = 0; j < 8; j++){
                float a = (float)o0[j]*w0 + (float)om[j]*wm + (float)op[j]*wp;
                float ns = (float)sv[j] + a * (1.f/3.f);
                outh[j] = (_Float16)ns;
            }
            *(half8*)(sg + prow*KP + e0) = outh;
        }
    }
}

// ---------------- fused f = A@W (zz=0) / A^T@W (zz=1, from AbT) -> LDS -------
// -> conv3x3 + tanh -> o16 + fused column-mean (atomicAdd into res).
// grid (bc, 4 row-strips, 2), block 256 (4 waves). Strip rs covers output rows
// [rs*32, rs*32+32); ftile holds f rows [rs*32-8, rs*32+40) (OOB zeroed).
// Phase 2: preload ALL 10 ch0 rows as branchless clamped+masked register loads
// (10 independent dwordx4 in flight -> HBM latency off the critical path),
// then 4 row-pair conv iterations of pure reg/LDS compute.
__global__ __launch_bounds__(256, 4) void f_conv_kernel(
    const _Float16* __restrict__ Ab, const _Float16* __restrict__ AbT,
    const _Float16* __restrict__ Wt,
    const _Float16* __restrict__ sf1, const _Float16* __restrict__ sf2,
    const float* __restrict__ pw,
    _Float16* __restrict__ o16_1, _Float16* __restrict__ o16_2,
    float* __restrict__ res, int b0, int seg)
{
    __shared__ _Float16 ftile[48][328];          // +8 pad: de-conflict phase-1 writes

    int bl = blockIdx.x, rs = blockIdx.y, zz = blockIdx.z;
    int R0 = rs*32 - 8;
    int tid = threadIdx.x, w = tid >> 6, lane = tid & 63;
    int m = lane & 15, quad = lane >> 4;

    // conv weights (uniform loads)
    const unsigned* pu = (const unsigned*)pw;
    h2 w01[2][3], w12[2][3];
    float w0f[2][3], w2f[2][3];
    #pragma unroll
    for (int c = 0; c < 2; c++)
        #pragma unroll
        for (int dy = 0; dy < 3; dy++){
            int rem = c*3 + dy;
            w01[c][dy] = __builtin_bit_cast(h2, pu[rem]);
            w12[c][dy] = __builtin_bit_cast(h2, pu[6 + rem]);
            w0f[c][dy] = pw[12 + rem];
            w2f[c][dy] = pw[18 + rem];
        }
    float bias = pw[24];

    // ---- phase 1: f rows [R0, R0+48) x cols 0..303 via MFMA ----
    const _Float16* gA = (zz ? AbT : Ab) + (size_t)bl*SS*SS;
    #pragma unroll
    for (int rg = 0; rg < 3; rg++){
        int gar = R0 + rg*16 + m;                      // A row for this lane
        int gac = gar < 0 ? 0 : (gar > SS-1 ? SS-1 : gar);   // clamp (OOB rows zeroed below)
        half8 a[4];
        #pragma unroll
        for (int kc = 0; kc < 4; kc++)
            a[kc] = *(const half8*)(gA + gac*SS + kc*32 + quad*8);
        #pragma unroll
        for (int ci = 0; ci < 5; ci++){
            int c = w + ci*4;                          // wave-strided col frags
            if (c < 19){
                int e = c*16 + m;                      // 0..303
                f32x4 acc = (f32x4){0.f,0.f,0.f,0.f};
                #pragma unroll
                for (int kc = 0; kc < 4; kc++){
                    half8 b = *(const half8*)(Wt + (size_t)e*SS + kc*32 + quad*8);
                    acc = __builtin_amdgcn_mfma_f32_16x16x32_f16(a[kc], b, acc, 0, 0, 0);
                }
                #pragma unroll
                for (int r = 0; r < 4; r++){
                    int lr = rg*16 + quad*4 + r;
                    int gf = R0 + lr;
                    bool ok = (gf >= 0) && (gf < SS) && (e < EE);
                    ftile[lr][e] = ok ? (_Float16)acc[r] : (_Float16)0.f;
                }
            }
        }
    }
    // zero-fill cols 304..319 (uniform padding for conv)
    for (int idx = tid; idx < 48*16; idx += 256)
        ftile[idx >> 4][304 + (idx & 15)] = (_Float16)0.f;
    __syncthreads();

    // ---- phase 2: conv(3x3, ch0=sf regs, ch1=f LDS) + tanh -> o16 ----
    const _Float16* cs = (zz ? sf2 : sf1) + (size_t)bl*SS*KP;
    _Float16* od = (zz ? o16_2 : o16_1) + (size_t)bl*SS*KP;
    int l = lane, e0 = l*8;
    bool lok = (l < 40);
    int eok = lok ? e0 : 0;                       // dead lanes load col 0 (masked)
    float msum[8];
    #pragma unroll
    for (int j = 0; j < 8; j++) msum[j] = 0.f;

    // preload all 10 ch0 rows (branchless clamped loads, masked to zero)
    half8 s[10];
    int rbase = rs*32 + w*8 - 1;
    #pragma unroll
    for (int q = 0; q < 10; q++){
        int gr = rbase + q;
        int gc = gr < 0 ? 0 : (gr > SS-1 ? SS-1 : gr);
        half8 t = *(const half8*)(cs + gc*KP + eok);
        bool ok = (gr >= 0) && (gr < SS) && lok;
        s[q] = ok ? t : (half8){};
    }

    #pragma unroll
    for (int p = 0; p < 4; p++){
        int roA = rs*32 + w*8 + 2*p;            // output rows roA, roA+1
        int lrA = w*8 + 2*p + 8;                // ftile local row of roA
        float accA[8], accB[8];
        #pragma unroll
        for (int j = 0; j < 8; j++){ accA[j] = bias; accB[j] = bias; }

        #pragma unroll
        for (int c = 0; c < 2; c++){
            #pragma unroll
            for (int q = 0; q < 4; q++){        // input row = roA - 1 + q
                half8 hv;
                if (c == 0){
                    hv = s[2*p + q];
                } else {
                    hv = *(const half8*)&ftile[lrA - 1 + q][eok];
                    if (!lok) hv = (half8){};
                }
                h2 d0 = __builtin_shufflevector(hv, hv, 0, 1);
                h2 d1 = __builtin_shufflevector(hv, hv, 2, 3);
                h2 d2 = __builtin_shufflevector(hv, hv, 4, 5);
                h2 d3 = __builtin_shufflevector(hv, hv, 6, 7);
                int dmi = __shfl_up(__builtin_bit_cast(int, d3), 1);
                int dpi = __shfl_down(__builtin_bit_cast(int, d0), 1);
                h2 dmh = __builtin_bit_cast(h2, dmi);
                h2 dph = __builtin_bit_cast(h2, dpi);
                float xm = (l == 0) ? 0.f : (float)dmh[1];
                float xp = (float)dph[0];
                if (q <= 2)
                    conv_row(accA, w01[c][q], w12[c][q], w0f[c][q], w2f[c][q],
                             d0, d1, d2, d3, xm, xp);
                if (q >= 1)
                    conv_row(accB, w01[c][q-1], w12[c][q-1], w0f[c][q-1], w2f[c][q-1],
                             d0, d1, d2, d3, xm, xp);
            }
        }

        half8 outA, outB;
        #pragma unroll
        for (int j = 0; j < 8; j++){
            bool ev = (e0 + j < EE);
            float tA = ev ? fast_tanh(accA[j]) : 0.f;
            float tB = ev ? fast_tanh(accB[j]) : 0.f;
            outA[j] = (_Float16)tA;
            outB[j] = (_Float16)tB;
            msum[j] += tA + tB;
        }
        if (lok){
            *(half8*)(od + roA*KP + e0) = outA;
            *(half8*)(od + (roA+1)*KP + e0) = outB;
        }
    }

    // ---- fused column-mean: LDS partial over 4 waves, atomicAdd into res ----
    __syncthreads();                             // all ftile reads done
    float* mred = (float*)&ftile[0][0];          // alias: [4][320] floats
    if (lok){
        #pragma unroll
        for (int j = 0; j < 8; j++) mred[w*320 + e0 + j] = msum[j];
    }
    __syncthreads();
    for (int e = tid; e < EE; e += 256){
        float s2 = mred[e] + mred[320+e] + mred[640+e] + mred[960+e];
        atomicAdd(&res[(size_t)(b0+bl)*FCIN + zz*900 + seg*300 + e], s2 * (1.f/SS));
    }
}

// ---------------- fc1: K-split x6, atomic accumulate into h ------------------
// grid (8,5,6), block 256; h must be zeroed before launch
#define CKK 12
__global__ __launch_bounds__(256) void fc1_kernel(const float* __restrict__ res,
                                                  const float* __restrict__ fw,
                                                  float* __restrict__ h){
    __shared__ float Xt[CKK][68];
    __shared__ float Wts[CKK][68];
    int bt = blockIdx.x, jt = blockIdx.y, kz = blockIdx.z;
    int tid = threadIdx.x, tx = tid & 15, ty = tid >> 4;
    int b0l = bt*64, j0 = jt*64, kbase = kz*300;
    float acc[4][4] = {};
    for (int k0 = 0; k0 < 300; k0 += CKK){
        #pragma unroll
        for (int u = 0; u < 3; u++){
            int idx = tid + u*256;
            int a = idx / CKK, k = idx - a*CKK;
            Xt[k][a] = res[(size_t)(b0l+a)*FCIN + kbase + k0 + k];
            int gj = j0 + a;
            Wts[k][a] = (gj < HH) ? fw[(size_t)gj*FCIN + kbase + k0 + k] : 0.f;
        }
        __syncthreads();
        #pragma unroll
        for (int k = 0; k < CKK; k++){
            float xv[4], wv[4];
            #pragma unroll
            for (int r = 0; r < 4; r++) xv[r] = Xt[k][ty*4+r];
            #pragma unroll
            for (int c = 0; c < 4; c++) wv[c] = Wts[k][tx*4+c];
            #pragma unroll
            for (int r = 0; r < 4; r++)
                #pragma unroll
                for (int c = 0; c < 4; c++)
                    acc[r][c] = fmaf(xv[r], wv[c], acc[r][c]);
        }
        __syncthreads();
    }
    #pragma unroll
    for (int r = 0; r < 4; r++){
        int gb = b0l + ty*4 + r;
        #pragma unroll
        for (int c = 0; c < 4; c++){
            int gj = j0 + tx*4 + c;
            if (gj < HH) atomicAdd(&h[(size_t)gb*HH + gj], acc[r][c]);
        }
    }
}

// ---------------- layernorm + relu + fc2 + softmax (+fc1 bias) ---------------
__global__ void head_kernel(const float* __restrict__ h, const float* __restrict__ fb,
                            const float* __restrict__ g,
                            const float* __restrict__ be, const float* __restrict__ f2w,
                            const float* __restrict__ f2b, float* __restrict__ out){
    int b = blockIdx.x, tid = threadIdx.x;
    __shared__ float arr[HH];
    __shared__ float s_s[4], s_q[4], r0[4], r1[4];
    float x0 = (tid < HH) ? h[(size_t)b*HH + tid] + fb[tid] : 0.f;
    float x1 = (tid + 256 < HH) ? h[(size_t)b*HH + tid + 256] + fb[tid+256] : 0.f;
    float s = x0 + x1, sq = x0*x0 + x1*x1;
    #pragma unroll
    for (int o = 32; o > 0; o >>= 1){ s += __shfl_down(s, o); sq += __shfl_down(sq, o); }
    int wv = tid >> 6, ln = tid & 63;
    if (ln == 0){ s_s[wv] = s; s_q[wv] = sq; }
    __syncthreads();
    s  = s_s[0] + s_s[1] + s_s[2] + s_s[3];
    sq = s_q[0] + s_q[1] + s_q[2] + s_q[3];
    float mean = s / HH;
    float var = sq / HH - mean*mean;
    float inv = rsqrtf(var + 1e-5f);
    if (tid < HH)       arr[tid]     = fmaxf((x0 - mean)*inv*g[tid]     + be[tid],     0.f);
    if (tid + 256 < HH) arr[tid+256] = fmaxf((x1 - mean)*inv*g[tid+256] + be[tid+256], 0.f);
    __syncthreads();
    float p0 = 0.f, p1 = 0.f;
    for (int j = tid; j < HH; j += 256){ float hv = arr[j]; p0 += hv*f2w[j]; p1 += hv*f2w[HH+j]; }
    #pragma unroll
    for (int o = 32; o > 0; o >>= 1){ p0 += __shfl_down(p0, o); p1 += __shfl_down(p1, o); }
    if (ln == 0){ r0[wv] = p0; r1[wv] = p1; }
    __syncthreads();
    if (tid == 0){
        float o0 = r0[0]+r0[1]+r0[2]+r0[3] + f2b[0];
        float o1 = r1[0]+r1[1]+r1[2]+r1[3] + f2b[1];
        out[b*2+0] = o0; out[b*2+1] = o1;
        float m = fmaxf(o0, o1);
        float e0 = __expf(o0 - m), e1 = __expf(o1 - m);
        float den = e0 + e1;
        out[BB*2 + b*2+0] = e0/den;
        out[BB*2 + b*2+1] = e1/den;
    }
}

extern "C" void kernel_launch(void* const* d_in, const int* in_sizes, int n_in,
                              void* d_out, int out_size, void* d_ws, size_t ws_size,
                              hipStream_t stream){
    const int*   seq1   = (const int*)d_in[0];
    const int*   seq2   = (const int*)d_in[1];
    const float* emb    = (const float*)d_in[2];
    const float* W      = (const float*)d_in[3];
    const float* conv_w = (const float*)d_in[4];
    const float* conv_b = (const float*)d_in[5];
    const float* fc1_w  = (const float*)d_in[6];
    const float* fc1_b  = (const float*)d_in[7];
    const float* ln_g   = (const float*)d_in[8];
    const float* ln_b   = (const float*)d_in[9];
    const float* fc2_w  = (const float*)d_in[10];
    const float* fc2_b  = (const float*)d_in[11];
    float* out = (float*)d_out;

    float* ws = (float*)d_ws;
    size_t fixedf = (size_t)BB*FCIN + (size_t)BB*HH + (size_t)KP*SS + 64;
    // per-batch floats: sf16 + o16 (each 2*SS*KP halves) + Ab + AbT + 2 vecs
    size_t perb = (size_t)2*SS*KP + (size_t)(SS*SS) + 2*SS;
    size_t avail = ws_size / 4;
    long long bcl = (long long)((avail > fixedf ? avail - fixedf : 0) / perb);
    int BC = (int)(bcl < 1 ? 1 : (bcl > BB ? BB : bcl));

    float* res = ws;
    float* hb  = res + (size_t)BB*FCIN;
    _Float16* Wt = (_Float16*)(hb + (size_t)BB*HH);
    float* pwt = (float*)(Wt + (size_t)2*KP*SS);
    _Float16* sf1 = (_Float16*)(pwt + 64);
    _Float16* sf2 = sf1 + (size_t)BC*SS*KP;
    _Float16* o16_1 = sf2 + (size_t)BC*SS*KP;
    _Float16* o16_2 = o16_1 + (size_t)BC*SS*KP;
    _Float16* Ab  = o16_2 + (size_t)BC*SS*KP;
    _Float16* AbT = Ab + (size_t)BC*SS*SS;
    float* v1  = (float*)(AbT + (size_t)BC*SS*SS);
    float* v2  = v1 + (size_t)BC*SS;

    wt_build_kernel<<<(2*KP*SS + 255)/256, 256, 0, stream>>>(W, Wt);
    cwpack_kernel<<<1, 64, 0, stream>>>(conv_w, conv_b, pwt);
    hipMemsetAsync(hb, 0, (size_t)BB*HH*sizeof(float), stream);
    hipMemsetAsync(res, 0, (size_t)BB*FCIN*sizeof(float), stream);

    for (int b0 = 0; b0 < BB; b0 += BC){
        int bc = (BB - b0 < BC) ? (BB - b0) : BC;
        embed_kernel<<<dim3(bc, 32, 2), 256, 0, stream>>>(seq1, seq2, emb, sf1, sf2,
                                                          v1, v2, res, b0);
        for (int it = 0; it < LLI; it++){
            cross_matchA<<<bc, 512, 0, stream>>>(sf1, sf2, v1, v2, Ab, AbT);
            f_conv_kernel<<<dim3(bc, 4, 2), 256, 0, stream>>>(Ab, AbT, Wt + (size_t)it*KP*SS,
                                                              sf1, sf2, pwt + it*32,
                                                              o16_1, o16_2, res, b0, it+1);
            cross_sums_pool<<<bc, 512, 0, stream>>>(o16_1, o16_2, v1, v2, sf1, sf2);
        }
    }
    fc1_kernel<<<dim3(8, 5, 6), 256, 0, stream>>>(res, fc1_w, hb);
    head_kernel<<<BB, 256, 0, stream>>>(hb, fc1_b, ln_g, ln_b, fc2_w, fc2_b, out);
}

// Round 9
// 736.188 us; speedup vs baseline: 1.2390x; 1.0076x over previous
//
#include <hip/hip_runtime.h>
#include <math.h>

#define BB 512
#define SS 128
#define EE 300
#define HH 300
#define FCIN 1800
#define LLI 2
#define KP 320          // padded K / leading dim for fp16 tensors

using half8 = __attribute__((ext_vector_type(8))) _Float16;
using h2    = __attribute__((ext_vector_type(2))) _Float16;
using f32x4 = __attribute__((ext_vector_type(4))) float;

__device__ __forceinline__ float fast_tanh(float x){
    float ax = fabsf(x);
    float t = __expf(-2.f*ax);
    float r = (1.f - t) * __builtin_amdgcn_rcpf(1.f + t);
    return copysignf(r, x);
}

// 1/(1+sqrt(max(x,0))) with HW approx ops (err ~1e-7 << 7.8e-3 tolerance)
__device__ __forceinline__ float inv1p_sqrt(float x){
    float d = __builtin_amdgcn_sqrtf(fmaxf(x, 0.f));
    return __builtin_amdgcn_rcpf(1.f + d);
}

// norm accumulate of a half8 via 4 fdot2 (constant-index pair extraction)
__device__ __forceinline__ float norm8(half8 hv, float n){
    h2 p0 = __builtin_shufflevector(hv, hv, 0, 1);
    h2 p1 = __builtin_shufflevector(hv, hv, 2, 3);
    h2 p2 = __builtin_shufflevector(hv, hv, 4, 5);
    h2 p3 = __builtin_shufflevector(hv, hv, 6, 7);
    n = __builtin_amdgcn_fdot2(p0, p0, n, false);
    n = __builtin_amdgcn_fdot2(p1, p1, n, false);
    n = __builtin_amdgcn_fdot2(p2, p2, n, false);
    n = __builtin_amdgcn_fdot2(p3, p3, n, false);
    return n;
}

// one conv row-tap: acc[0..7] += W0*left + (W1,W2)-dot2 pattern over d0..d3
__device__ __forceinline__ void conv_row(float* acc, h2 W01, h2 W12, float W0, float W2,
                                         h2 d0, h2 d1, h2 d2, h2 d3, float xm, float xp){
    acc[0] = fmaf(W0, xm,            __builtin_amdgcn_fdot2(W12, d0, acc[0], false));
    acc[1] = fmaf(W2, (float)d1[0],  __builtin_amdgcn_fdot2(W01, d0, acc[1], false));
    acc[2] = fmaf(W0, (float)d0[1],  __builtin_amdgcn_fdot2(W12, d1, acc[2], false));
    acc[3] = fmaf(W2, (float)d2[0],  __builtin_amdgcn_fdot2(W01, d1, acc[3], false));
    acc[4] = fmaf(W0, (float)d1[1],  __builtin_amdgcn_fdot2(W12, d2, acc[4], false));
    acc[5] = fmaf(W2, (float)d3[0],  __builtin_amdgcn_fdot2(W01, d2, acc[5], false));
    acc[6] = fmaf(W0, (float)d2[1],  __builtin_amdgcn_fdot2(W12, d3, acc[6], false));
    acc[7] = fmaf(W2, xp,            __builtin_amdgcn_fdot2(W01, d3, acc[7], false));
}

// ---------------- Wt build: Wt[it][e][j] = W[it][j][e], fp16, e zero-padded to 320
__global__ void wt_build_kernel(const float* __restrict__ W, _Float16* __restrict__ Wt){
    int idx = blockIdx.x*256 + threadIdx.x;      // 2*320*128 = 81920
    if (idx >= 2*KP*SS) return;
    int j = idx & 127;
    int e = (idx >> 7) % KP;
    int it = idx / (KP*SS);
    float v = (e < EE) ? W[(size_t)it*SS*EE + j*EE + e] : 0.f;
    Wt[idx] = (_Float16)v;
}

// ---------------- pack conv weights: per it, 32 dwords:
// [0..5] h2(w0,w1) per (c,dy); [6..11] h2(w1,w2); [12..17] f32 w0; [18..23] f32 w2; [24] bias
__global__ void cwpack_kernel(const float* __restrict__ cw, const float* __restrict__ cb,
                              float* __restrict__ pwt){
    int t = threadIdx.x;
    if (t < 12){
        int it = t / 6, rem = t % 6;          // rem = c*3+dy
        const float* w = cw + it*18 + rem*3;
        float a = w[0], b = w[1], d = w[2];
        h2 p01 = { (_Float16)a, (_Float16)b };
        h2 p12 = { (_Float16)b, (_Float16)d };
        float* o = pwt + it*32;
        ((unsigned*)o)[rem]   = __builtin_bit_cast(unsigned, p01);
        ((unsigned*)o)[6+rem] = __builtin_bit_cast(unsigned, p12);
        o[12+rem] = a;
        o[18+rem] = d;
    }
    if (t < 2) pwt[t*32+24] = cb[t];
}

// ---------------- embed: gather -> sf16 + valid mask + fused seg-0 mean ------
// grid (bc, 32, 2), block 256 (4 waves, wave = 1 row); res must be zeroed
__global__ __launch_bounds__(256) void embed_kernel(
    const int* __restrict__ seq1, const int* __restrict__ seq2,
    const float* __restrict__ emb,
    _Float16* __restrict__ sf1, _Float16* __restrict__ sf2,
    float* __restrict__ v1, float* __restrict__ v2,
    float* __restrict__ res, int b0){
    __shared__ float mred[4][320];
    int bl = blockIdx.x, which = blockIdx.z;
    int w = threadIdx.x >> 6;
    int r = blockIdx.y*4 + w;
    int l = threadIdx.x & 63;
    const int* seq = which ? seq2 : seq1;
    _Float16* sfg = (which ? sf2 : sf1) + (size_t)bl*SS*KP;
    float* vd = (which ? v2 : v1) + bl*SS;
    int token = seq[(size_t)(b0+bl)*SS + r];
    if (l == 0) vd[r] = (token != 0) ? 1.f : 0.f;
    const float* er = emb + (size_t)token * EE;
    int e0 = l*8;
    float x[8];
    if (l < 37){
        float4 a = *(const float4*)(er + e0);
        float4 b = *(const float4*)(er + e0 + 4);
        x[0]=a.x; x[1]=a.y; x[2]=a.z; x[3]=a.w;
        x[4]=b.x; x[5]=b.y; x[6]=b.z; x[7]=b.w;
    } else if (l == 37){
        x[0]=er[296]; x[1]=er[297]; x[2]=er[298]; x[3]=er[299];
        x[4]=0.f; x[5]=0.f; x[6]=0.f; x[7]=0.f;
    } else {
        #pragma unroll
        for (int j = 0; j < 8; j++) x[j] = 0.f;
    }
    if (l < 40){
        half8 hv;
        #pragma unroll
        for (int j = 0; j < 8; j++) hv[j] = (_Float16)x[j];
        *(half8*)(sfg + r*KP + e0) = hv;
        #pragma unroll
        for (int j = 0; j < 8; j++) mred[w][e0 + j] = x[j];
    }
    __syncthreads();
    for (int e = threadIdx.x; e < EE; e += 256){
        float s = mred[0][e] + mred[1][e] + mred[2][e] + mred[3][e];
        atomicAdd(&res[(size_t)(b0+bl)*FCIN + which*900 + e], s * (1.f/SS));
    }
}

// ---------------- MFMA match (A-producing): stages sf16*v, self-computes norms
// block 512 (8 waves); wave = 16 rows x 128 cols. Writes Ab AND AbT.
// 1-ahead register prefetch: next chunk's global loads issued between the
// barriers so they fly during the MFMA section (syncthreads drains vmcnt,
// so loads must NOT be in flight at the first barrier).
__global__ __launch_bounds__(512, 4) void cross_matchA(
    const _Float16* __restrict__ sfA, const _Float16* __restrict__ sfB,
    const float* __restrict__ vAg, const float* __restrict__ vBg,
    _Float16* __restrict__ Ab16, _Float16* __restrict__ AbT16)
{
    __shared__ _Float16 As[128][40];
    __shared__ _Float16 Bs[128][40];
    __shared__ float nAl[128], nBl[128], vAl[128], vBl[128];

    int bl = blockIdx.x;
    int tid = threadIdx.x;
    int w = tid >> 6, lane = tid & 63;
    int m = lane & 15, quad = lane >> 4;

    const _Float16* gA = sfA + (size_t)bl*SS*KP;
    const _Float16* gB = sfB + (size_t)bl*SS*KP;

    if (tid < 128){ vAl[tid] = vAg[bl*SS + tid]; }
    else if (tid < 256){ vBl[tid-128] = vBg[bl*SS + tid-128]; }

    f32x4 acc[8];
    #pragma unroll
    for (int c = 0; c < 8; c++) acc[c] = (f32x4){0.f,0.f,0.f,0.f};

    int srow = tid >> 2, skq = (tid & 3) * 8;
    int arow = w*16 + m;
    float nA = 0.f, nB = 0.f;

    half8 ha = *(const half8*)(gA + srow*KP + skq);     // chunk 0
    half8 hb = *(const half8*)(gB + srow*KP + skq);
    __syncthreads();                                    // vAl/vBl visible

    for (int kc = 0; kc < 10; kc++){
        {
            half8 sa = ha * (_Float16)vAl[srow];
            half8 sb = hb * (_Float16)vBl[srow];
            *(half8*)&As[srow][skq] = sa;
            *(half8*)&Bs[srow][skq] = sb;
            nA = norm8(sa, nA);
            nB = norm8(sb, nB);
        }
        __syncthreads();                                // stores visible; nothing in flight
        if (kc < 9){                                    // prefetch flies during MFMA
            ha = *(const half8*)(gA + srow*KP + (kc+1)*32 + skq);
            hb = *(const half8*)(gB + srow*KP + (kc+1)*32 + skq);
        }
        half8 a = *(const half8*)&As[arow][quad*8];
        #pragma unroll
        for (int c = 0; c < 8; c++){
            half8 b = *(const half8*)&Bs[c*16 + m][quad*8];
            acc[c] = __builtin_amdgcn_mfma_f32_16x16x32_f16(a, b, acc[c], 0, 0, 0);
        }
        __syncthreads();                                // reads done; drain ~finished prefetch
    }

    nA += __shfl_xor(nA, 1); nA += __shfl_xor(nA, 2);
    nB += __shfl_xor(nB, 1); nB += __shfl_xor(nB, 2);
    if ((tid & 3) == 0){ nAl[srow] = nA; nBl[srow] = nB; }
    __syncthreads();

    int ibase = w*16 + quad*4;
    _Float16* Ao = Ab16 + (size_t)bl*SS*SS;
    _Float16* AoT = AbT16 + (size_t)bl*SS*SS;
    #pragma unroll
    for (int c = 0; c < 8; c++){
        int j = c*16 + m;
        float nc = nBl[j];
        #pragma unroll
        for (int r = 0; r < 4; r++){
            int i = ibase + r;
            float d2 = nAl[i] + nc - 2.f*acc[c][r];
            _Float16 val = (_Float16)inv1p_sqrt(d2);
            Ao[i*SS + j] = val;
            AoT[j*SS + i] = val;
        }
    }
}

// ---------------- MFMA match sums + fused pool/residual (norms self-computed)
// block 512; same 1-ahead prefetch staging as cross_matchA.
__global__ __launch_bounds__(512, 4) void cross_sums_pool(
    const _Float16* __restrict__ oA, const _Float16* __restrict__ oB,
    const float* __restrict__ vAg, const float* __restrict__ vBg,
    _Float16* __restrict__ sf1, _Float16* __restrict__ sf2)
{
    __shared__ _Float16 As[128][40];
    __shared__ _Float16 Bs[128][40];
    __shared__ float nAl[128], nBl[128], vAl[128], vBl[128];
    __shared__ float colred[8][132];
    __shared__ float wr[128], wc[128];

    int bl = blockIdx.x;
    int tid = threadIdx.x;
    int w = tid >> 6, lane = tid & 63;
    int m = lane & 15, quad = lane >> 4;

    const _Float16* gA = oA + (size_t)bl*SS*KP;
    const _Float16* gB = oB + (size_t)bl*SS*KP;

    if (tid < 128){ vAl[tid] = vAg[bl*SS + tid]; }
    else if (tid < 256){ vBl[tid-128] = vBg[bl*SS + tid-128]; }

    f32x4 acc[8];
    #pragma unroll
    for (int c = 0; c < 8; c++) acc[c] = (f32x4){0.f,0.f,0.f,0.f};

    int srow = tid >> 2, skq = (tid & 3) * 8;
    int arow = w*16 + m;
    float nA = 0.f, nB = 0.f;

    half8 ha = *(const half8*)(gA + srow*KP + skq);     // chunk 0
    half8 hb = *(const half8*)(gB + srow*KP + skq);
    __syncthreads();                                    // vAl/vBl visible

    for (int kc = 0; kc < 10; kc++){
        {
            half8 sa = ha * (_Float16)vAl[srow];
            half8 sb = hb * (_Float16)vBl[srow];
            *(half8*)&As[srow][skq] = sa;
            *(half8*)&Bs[srow][skq] = sb;
            nA = norm8(sa, nA);
            nB = norm8(sb, nB);
        }
        __syncthreads();
        if (kc < 9){
            ha = *(const half8*)(gA + srow*KP + (kc+1)*32 + skq);
            hb = *(const half8*)(gB + srow*KP + (kc+1)*32 + skq);
        }
        half8 a = *(const half8*)&As[arow][quad*8];
        #pragma unroll
        for (int c = 0; c < 8; c++){
            half8 b = *(const half8*)&Bs[c*16 + m][quad*8];
            acc[c] = __builtin_amdgcn_mfma_f32_16x16x32_f16(a, b, acc[c], 0, 0, 0);
        }
        __syncthreads();
    }

    nA += __shfl_xor(nA, 1); nA += __shfl_xor(nA, 2);
    nB += __shfl_xor(nB, 1); nB += __shfl_xor(nB, 2);
    if ((tid & 3) == 0){ nAl[srow] = nA; nBl[srow] = nB; }
    __syncthreads();

    int ibase = w*16 + quad*4;
    float aval[8][4];
    #pragma unroll
    for (int c = 0; c < 8; c++){
        float nc = nBl[c*16 + m];
        #pragma unroll
        for (int r = 0; r < 4; r++){
            float d2 = nAl[ibase+r] + nc - 2.f*acc[c][r];
            aval[c][r] = inv1p_sqrt(d2);
        }
    }

    // row sums -> wr
    float rp[4];
    #pragma unroll
    for (int r = 0; r < 4; r++){
        float s = 0.f;
        #pragma unroll
        for (int c = 0; c < 8; c++) s += aval[c][r];
        rp[r] = s;
    }
    #pragma unroll
    for (int mask = 1; mask < 16; mask <<= 1)
        #pragma unroll
        for (int r = 0; r < 4; r++) rp[r] += __shfl_xor(rp[r], mask);
    if (m == 0){
        #pragma unroll
        for (int r = 0; r < 4; r++) wr[ibase + r] = rp[r];
    }
    // col sums -> wc
    float cp[8];
    #pragma unroll
    for (int c = 0; c < 8; c++){
        float s = 0.f;
        #pragma unroll
        for (int r = 0; r < 4; r++) s += aval[c][r];
        cp[c] = s;
    }
    #pragma unroll
    for (int c = 0; c < 8; c++){
        cp[c] += __shfl_xor(cp[c], 16);
        cp[c] += __shfl_xor(cp[c], 32);
    }
    if (quad == 0){
        #pragma unroll
        for (int c = 0; c < 8; c++) colred[w][c*16 + m] = cp[c];
    }
    __syncthreads();
    if (tid < 128){
        float s = 0.f;
        #pragma unroll
        for (int g = 0; g < 8; g++) s += colred[g][tid];
        wc[tid] = s;
    }
    __syncthreads();

    // ---- fused pool epilogue: 4 lanes per row (tid>>2 = row, tid&3 = sub) ----
    int prow = tid >> 2, sub = tid & 3;
    #pragma unroll
    for (int which = 0; which < 2; which++){
        const _Float16* og = which ? gB : gA;
        const float* wv = which ? wc : wr;
        _Float16* sg = (which ? sf2 : sf1) + (size_t)bl*SS*KP;
        float w0 = wv[prow];
        float wm = (prow > 0)   ? wv[prow-1] : 0.f;
        float wp = (prow < 127) ? wv[prow+1] : 0.f;
        #pragma unroll
        for (int k = 0; k < 10; k++){
            int e0 = (sub + k*4) * 8;           // < 320
            half8 o0 = *(const half8*)(og + prow*KP + e0);
            half8 om = {};
            half8 op = {};
            if (prow > 0)   om = *(const half8*)(og + (prow-1)*KP + e0);
            if (prow < 127) op = *(const half8*)(og + (prow+1)*KP + e0);
            half8 sv = *(const half8*)(sg + prow*KP + e0);
            half8 outh;
            #pragma unroll
            for (int j = 0; j < 8; j++){
                float a = (float)o0[j]*w0 + (float)om[j]*wm + (float)op[j]*wp;
                float ns = (float)sv[j] + a * (1.f/3.f);
                outh[j] = (_Float16)ns;
            }
            *(half8*)(sg + prow*KP + e0) = outh;
        }
    }
}

// ---------------- fused f = A@W (zz=0) / A^T@W (zz=1, from AbT) -> LDS -------
// -> conv3x3 + tanh -> o16 + fused column-mean (atomicAdd into res).
// grid (bc, 4 row-strips, 2), block 256 (4 waves). Strip rs covers output rows
// [rs*32, rs*32+32); ftile holds f rows [rs*32-8, rs*32+40) (OOB zeroed).
// Phase 2: preload ALL 10 ch0 rows as branchless clamped+masked register loads
// (10 independent dwordx4 in flight -> HBM latency off the critical path),
// then 4 row-pair conv iterations of pure reg/LDS compute.
__global__ __launch_bounds__(256, 4) void f_conv_kernel(
    const _Float16* __restrict__ Ab, const _Float16* __restrict__ AbT,
    const _Float16* __restrict__ Wt,
    const _Float16* __restrict__ sf1, const _Float16* __restrict__ sf2,
    const float* __restrict__ pw,
    _Float16* __restrict__ o16_1, _Float16* __restrict__ o16_2,
    float* __restrict__ res, int b0, int seg)
{
    __shared__ _Float16 ftile[48][328];          // +8 pad: de-conflict phase-1 writes

    int bl = blockIdx.x, rs = blockIdx.y, zz = blockIdx.z;
    int R0 = rs*32 - 8;
    int tid = threadIdx.x, w = tid >> 6, lane = tid & 63;
    int m = lane & 15, quad = lane >> 4;

    // conv weights (uniform loads)
    const unsigned* pu = (const unsigned*)pw;
    h2 w01[2][3], w12[2][3];
    float w0f[2][3], w2f[2][3];
    #pragma unroll
    for (int c = 0; c < 2; c++)
        #pragma unroll
        for (int dy = 0; dy < 3; dy++){
            int rem = c*3 + dy;
            w01[c][dy] = __builtin_bit_cast(h2, pu[rem]);
            w12[c][dy] = __builtin_bit_cast(h2, pu[6 + rem]);
            w0f[c][dy] = pw[12 + rem];
            w2f[c][dy] = pw[18 + rem];
        }
    float bias = pw[24];

    // ---- phase 1: f rows [R0, R0+48) x cols 0..303 via MFMA ----
    const _Float16* gA = (zz ? AbT : Ab) + (size_t)bl*SS*SS;
    #pragma unroll
    for (int rg = 0; rg < 3; rg++){
        int gar = R0 + rg*16 + m;                      // A row for this lane
        int gac = gar < 0 ? 0 : (gar > SS-1 ? SS-1 : gar);   // clamp (OOB rows zeroed below)
        half8 a[4];
        #pragma unroll
        for (int kc = 0; kc < 4; kc++)
            a[kc] = *(const half8*)(gA + gac*SS + kc*32 + quad*8);
        #pragma unroll
        for (int ci = 0; ci < 5; ci++){
            int c = w + ci*4;                          // wave-strided col frags
            if (c < 19){
                int e = c*16 + m;                      // 0..303
                f32x4 acc = (f32x4){0.f,0.f,0.f,0.f};
                #pragma unroll
                for (int kc = 0; kc < 4; kc++){
                    half8 b = *(const half8*)(Wt + (size_t)e*SS + kc*32 + quad*8);
                    acc = __builtin_amdgcn_mfma_f32_16x16x32_f16(a[kc], b, acc, 0, 0, 0);
                }
                #pragma unroll
                for (int r = 0; r < 4; r++){
                    int lr = rg*16 + quad*4 + r;
                    int gf = R0 + lr;
                    bool ok = (gf >= 0) && (gf < SS) && (e < EE);
                    ftile[lr][e] = ok ? (_Float16)acc[r] : (_Float16)0.f;
                }
            }
        }
    }
    // zero-fill cols 304..319 (uniform padding for conv)
    for (int idx = tid; idx < 48*16; idx += 256)
        ftile[idx >> 4][304 + (idx & 15)] = (_Float16)0.f;
    __syncthreads();

    // ---- phase 2: conv(3x3, ch0=sf regs, ch1=f LDS) + tanh -> o16 ----
    const _Float16* cs = (zz ? sf2 : sf1) + (size_t)bl*SS*KP;
    _Float16* od = (zz ? o16_2 : o16_1) + (size_t)bl*SS*KP;
    int l = lane, e0 = l*8;
    bool lok = (l < 40);
    int eok = lok ? e0 : 0;                       // dead lanes load col 0 (masked)
    float msum[8];
    #pragma unroll
    for (int j = 0; j < 8; j++) msum[j] = 0.f;

    // preload all 10 ch0 rows (branchless clamped loads, masked to zero)
    half8 s[10];
    int rbase = rs*32 + w*8 - 1;
    #pragma unroll
    for (int q = 0; q < 10; q++){
        int gr = rbase + q;
        int gc = gr < 0 ? 0 : (gr > SS-1 ? SS-1 : gr);
        half8 t = *(const half8*)(cs + gc*KP + eok);
        bool ok = (gr >= 0) && (gr < SS) && lok;
        s[q] = ok ? t : (half8){};
    }

    #pragma unroll
    for (int p = 0; p < 4; p++){
        int roA = rs*32 + w*8 + 2*p;            // output rows roA, roA+1
        int lrA = w*8 + 2*p + 8;                // ftile local row of roA
        float accA[8], accB[8];
        #pragma unroll
        for (int j = 0; j < 8; j++){ accA[j] = bias; accB[j] = bias; }

        #pragma unroll
        for (int c = 0; c < 2; c++){
            #pragma unroll
            for (int q = 0; q < 4; q++){        // input row = roA - 1 + q
                half8 hv;
                if (c == 0){
                    hv = s[2*p + q];
                } else {
                    hv = *(const half8*)&ftile[lrA - 1 + q][eok];
                    if (!lok) hv = (half8){};
                }
                h2 d0 = __builtin_shufflevector(hv, hv, 0, 1);
                h2 d1 = __builtin_shufflevector(hv, hv, 2, 3);
                h2 d2 = __builtin_shufflevector(hv, hv, 4, 5);
                h2 d3 = __builtin_shufflevector(hv, hv, 6, 7);
                int dmi = __shfl_up(__builtin_bit_cast(int, d3), 1);
                int dpi = __shfl_down(__builtin_bit_cast(int, d0), 1);
                h2 dmh = __builtin_bit_cast(h2, dmi);
                h2 dph = __builtin_bit_cast(h2, dpi);
                float xm = (l == 0) ? 0.f : (float)dmh[1];
                float xp = (float)dph[0];
                if (q <= 2)
                    conv_row(accA, w01[c][q], w12[c][q], w0f[c][q], w2f[c][q],
                             d0, d1, d2, d3, xm, xp);
                if (q >= 1)
                    conv_row(accB, w01[c][q-1], w12[c][q-1], w0f[c][q-1], w2f[c][q-1],
                             d0, d1, d2, d3, xm, xp);
            }
        }

        half8 outA, outB;
        #pragma unroll
        for (int j = 0; j < 8; j++){
            bool ev = (e0 + j < EE);
            float tA = ev ? fast_tanh(accA[j]) : 0.f;
            float tB = ev ? fast_tanh(accB[j]) : 0.f;
            outA[j] = (_Float16)tA;
            outB[j] = (_Float16)tB;
            msum[j] += tA + tB;
        }
        if (lok){
            *(half8*)(od + roA*KP + e0) = outA;
            *(half8*)(od + (roA+1)*KP + e0) = outB;
        }
    }

    // ---- fused column-mean: LDS partial over 4 waves, atomicAdd into res ----
    __syncthreads();                             // all ftile reads done
    float* mred = (float*)&ftile[0][0];          // alias: [4][320] floats
    if (lok){
        #pragma unroll
        for (int j = 0; j < 8; j++) mred[w*320 + e0 + j] = msum[j];
    }
    __syncthreads();
    for (int e = tid; e < EE; e += 256){
        float s2 = mred[e] + mred[320+e] + mred[640+e] + mred[960+e];
        atomicAdd(&res[(size_t)(b0+bl)*FCIN + zz*900 + seg*300 + e], s2 * (1.f/SS));
    }
}

// ---------------- fc1: K-split x6, atomic accumulate into h ------------------
// grid (8,5,6), block 256; h must be zeroed before launch
#define CKK 12
__global__ __launch_bounds__(256) void fc1_kernel(const float* __restrict__ res,
                                                  const float* __restrict__ fw,
                                                  float* __restrict__ h){
    __shared__ float Xt[CKK][68];
    __shared__ float Wts[CKK][68];
    int bt = blockIdx.x, jt = blockIdx.y, kz = blockIdx.z;
    int tid = threadIdx.x, tx = tid & 15, ty = tid >> 4;
    int b0l = bt*64, j0 = jt*64, kbase = kz*300;
    float acc[4][4] = {};
    for (int k0 = 0; k0 < 300; k0 += CKK){
        #pragma unroll
        for (int u = 0; u < 3; u++){
            int idx = tid + u*256;
            int a = idx / CKK, k = idx - a*CKK;
            Xt[k][a] = res[(size_t)(b0l+a)*FCIN + kbase + k0 + k];
            int gj = j0 + a;
            Wts[k][a] = (gj < HH) ? fw[(size_t)gj*FCIN + kbase + k0 + k] : 0.f;
        }
        __syncthreads();
        #pragma unroll
        for (int k = 0; k < CKK; k++){
            float xv[4], wv[4];
            #pragma unroll
            for (int r = 0; r < 4; r++) xv[r] = Xt[k][ty*4+r];
            #pragma unroll
            for (int c = 0; c < 4; c++) wv[c] = Wts[k][tx*4+c];
            #pragma unroll
            for (int r = 0; r < 4; r++)
                #pragma unroll
                for (int c = 0; c < 4; c++)
                    acc[r][c] = fmaf(xv[r], wv[c], acc[r][c]);
        }
        __syncthreads();
    }
    #pragma unroll
    for (int r = 0; r < 4; r++){
        int gb = b0l + ty*4 + r;
        #pragma unroll
        for (int c = 0; c < 4; c++){
            int gj = j0 + tx*4 + c;
            if (gj < HH) atomicAdd(&h[(size_t)gb*HH + gj], acc[r][c]);
        }
    }
}

// ---------------- layernorm + relu + fc2 + softmax (+fc1 bias) ---------------
__global__ void head_kernel(const float* __restrict__ h, const float* __restrict__ fb,
                            const float* __restrict__ g,
                            const float* __restrict__ be, const float* __restrict__ f2w,
                            const float* __restrict__ f2b, float* __restrict__ out){
    int b = blockIdx.x, tid = threadIdx.x;
    __shared__ float arr[HH];
    __shared__ float s_s[4], s_q[4], r0[4], r1[4];
    float x0 = (tid < HH) ? h[(size_t)b*HH + tid] + fb[tid] : 0.f;
    float x1 = (tid + 256 < HH) ? h[(size_t)b*HH + tid + 256] + fb[tid+256] : 0.f;
    float s = x0 + x1, sq = x0*x0 + x1*x1;
    #pragma unroll
    for (int o = 32; o > 0; o >>= 1){ s += __shfl_down(s, o); sq += __shfl_down(sq, o); }
    int wv = tid >> 6, ln = tid & 63;
    if (ln == 0){ s_s[wv] = s; s_q[wv] = sq; }
    __syncthreads();
    s  = s_s[0] + s_s[1] + s_s[2] + s_s[3];
    sq = s_q[0] + s_q[1] + s_q[2] + s_q[3];
    float mean = s / HH;
    float var = sq / HH - mean*mean;
    float inv = rsqrtf(var + 1e-5f);
    if (tid < HH)       arr[tid]     = fmaxf((x0 - mean)*inv*g[tid]     + be[tid],     0.f);
    if (tid + 256 < HH) arr[tid+256] = fmaxf((x1 - mean)*inv*g[tid+256] + be[tid+256], 0.f);
    __syncthreads();
    float p0 = 0.f, p1 = 0.f;
    for (int j = tid; j < HH; j += 256){ float hv = arr[j]; p0 += hv*f2w[j]; p1 += hv*f2w[HH+j]; }
    #pragma unroll
    for (int o = 32; o > 0; o >>= 1){ p0 += __shfl_down(p0, o); p1 += __shfl_down(p1, o); }
    if (ln == 0){ r0[wv] = p0; r1[wv] = p1; }
    __syncthreads();
    if (tid == 0){
        float o0 = r0[0]+r0[1]+r0[2]+r0[3] + f2b[0];
        float o1 = r1[0]+r1[1]+r1[2]+r1[3] + f2b[1];
        out[b*2+0] = o0; out[b*2+1] = o1;
        float m = fmaxf(o0, o1);
        float e0 = __expf(o0 - m), e1 = __expf(o1 - m);
        float den = e0 + e1;
        out[BB*2 + b*2+0] = e0/den;
        out[BB*2 + b*2+1] = e1/den;
    }
}

extern "C" void kernel_launch(void* const* d_in, const int* in_sizes, int n_in,
                              void* d_out, int out_size, void* d_ws, size_t ws_size,
                              hipStream_t stream){
    const int*   seq1   = (const int*)d_in[0];
    const int*   seq2   = (const int*)d_in[1];
    const float* emb    = (const float*)d_in[2];
    const float* W      = (const float*)d_in[3];
    const float* conv_w = (const float*)d_in[4];
    const float* conv_b = (const float*)d_in[5];
    const float* fc1_w  = (const float*)d_in[6];
    const float* fc1_b  = (const float*)d_in[7];
    const float* ln_g   = (const float*)d_in[8];
    const float* ln_b   = (const float*)d_in[9];
    const float* fc2_w  = (const float*)d_in[10];
    const float* fc2_b  = (const float*)d_in[11];
    float* out = (float*)d_out;

    float* ws = (float*)d_ws;
    size_t fixedf = (size_t)BB*FCIN + (size_t)BB*HH + (size_t)KP*SS + 64;
    // per-batch floats: sf16 + o16 (each 2*SS*KP halves) + Ab + AbT + 2 vecs
    size_t perb = (size_t)2*SS*KP + (size_t)(SS*SS) + 2*SS;
    size_t avail = ws_size / 4;
    long long bcl = (long long)((avail > fixedf ? avail - fixedf : 0) / perb);
    int BC = (int)(bcl < 1 ? 1 : (bcl > BB ? BB : bcl));

    float* res = ws;
    float* hb  = res + (size_t)BB*FCIN;
    _Float16* Wt = (_Float16*)(hb + (size_t)BB*HH);
    float* pwt = (float*)(Wt + (size_t)2*KP*SS);
    _Float16* sf1 = (_Float16*)(pwt + 64);
    _Float16* sf2 = sf1 + (size_t)BC*SS*KP;
    _Float16* o16_1 = sf2 + (size_t)BC*SS*KP;
    _Float16* o16_2 = o16_1 + (size_t)BC*SS*KP;
    _Float16* Ab  = o16_2 + (size_t)BC*SS*KP;
    _Float16* AbT = Ab + (size_t)BC*SS*SS;
    float* v1  = (float*)(AbT + (size_t)BC*SS*SS);
    float* v2  = v1 + (size_t)BC*SS;

    wt_build_kernel<<<(2*KP*SS + 255)/256, 256, 0, stream>>>(W, Wt);
    cwpack_kernel<<<1, 64, 0, stream>>>(conv_w, conv_b, pwt);
    hipMemsetAsync(hb, 0, (size_t)BB*HH*sizeof(float), stream);
    hipMemsetAsync(res, 0, (size_t)BB*FCIN*sizeof(float), stream);

    for (int b0 = 0; b0 < BB; b0 += BC){
        int bc = (BB - b0 < BC) ? (BB - b0) : BC;
        embed_kernel<<<dim3(bc, 32, 2), 256, 0, stream>>>(seq1, seq2, emb, sf1, sf2,
                                                          v1, v2, res, b0);
        for (int it = 0; it < LLI; it++){
            cross_matchA<<<bc, 512, 0, stream>>>(sf1, sf2, v1, v2, Ab, AbT);
            f_conv_kernel<<<dim3(bc, 4, 2), 256, 0, stream>>>(Ab, AbT, Wt + (size_t)it*KP*SS,
                                                              sf1, sf2, pwt + it*32,
                                                              o16_1, o16_2, res, b0, it+1);
            cross_sums_pool<<<bc, 512, 0, stream>>>(o16_1, o16_2, v1, v2, sf1, sf2);
        }
    }
    fc1_kernel<<<dim3(8, 5, 6), 256, 0, stream>>>(res, fc1_w, hb);
    head_kernel<<<BB, 256, 0, stream>>>(hb, fc1_b, ln_g, ln_b, fc2_w, fc2_b, out);
}

// Round 10
// 643.212 us; speedup vs baseline: 1.4181x; 1.1445x over previous
//
#include <hip/hip_runtime.h>
#include <math.h>

#define BB 512
#define SS 128
#define EE 300
#define HH 300
#define FCIN 1800
#define LLI 2
#define KP 320          // padded K / leading dim for fp16 tensors

using half8 = __attribute__((ext_vector_type(8))) _Float16;
using h2    = __attribute__((ext_vector_type(2))) _Float16;
using f32x4 = __attribute__((ext_vector_type(4))) float;

__device__ __forceinline__ float fast_tanh(float x){
    float ax = fabsf(x);
    float t = __expf(-2.f*ax);
    float r = (1.f - t) * __builtin_amdgcn_rcpf(1.f + t);
    return copysignf(r, x);
}

// 1/(1+sqrt(max(x,0))) with HW approx ops (err ~1e-7 << 7.8e-3 tolerance)
__device__ __forceinline__ float inv1p_sqrt(float x){
    float d = __builtin_amdgcn_sqrtf(fmaxf(x, 0.f));
    return __builtin_amdgcn_rcpf(1.f + d);
}

// norm accumulate of a half8 via 4 fdot2 (constant-index pair extraction)
__device__ __forceinline__ float norm8(half8 hv, float n){
    h2 p0 = __builtin_shufflevector(hv, hv, 0, 1);
    h2 p1 = __builtin_shufflevector(hv, hv, 2, 3);
    h2 p2 = __builtin_shufflevector(hv, hv, 4, 5);
    h2 p3 = __builtin_shufflevector(hv, hv, 6, 7);
    n = __builtin_amdgcn_fdot2(p0, p0, n, false);
    n = __builtin_amdgcn_fdot2(p1, p1, n, false);
    n = __builtin_amdgcn_fdot2(p2, p2, n, false);
    n = __builtin_amdgcn_fdot2(p3, p3, n, false);
    return n;
}

// one conv row-tap: acc[0..7] += W0*left + (W1,W2)-dot2 pattern over d0..d3
__device__ __forceinline__ void conv_row(float* acc, h2 W01, h2 W12, float W0, float W2,
                                         h2 d0, h2 d1, h2 d2, h2 d3, float xm, float xp){
    acc[0] = fmaf(W0, xm,            __builtin_amdgcn_fdot2(W12, d0, acc[0], false));
    acc[1] = fmaf(W2, (float)d1[0],  __builtin_amdgcn_fdot2(W01, d0, acc[1], false));
    acc[2] = fmaf(W0, (float)d0[1],  __builtin_amdgcn_fdot2(W12, d1, acc[2], false));
    acc[3] = fmaf(W2, (float)d2[0],  __builtin_amdgcn_fdot2(W01, d1, acc[3], false));
    acc[4] = fmaf(W0, (float)d1[1],  __builtin_amdgcn_fdot2(W12, d2, acc[4], false));
    acc[5] = fmaf(W2, (float)d3[0],  __builtin_amdgcn_fdot2(W01, d2, acc[5], false));
    acc[6] = fmaf(W0, (float)d2[1],  __builtin_amdgcn_fdot2(W12, d3, acc[6], false));
    acc[7] = fmaf(W2, xp,            __builtin_amdgcn_fdot2(W01, d3, acc[7], false));
}

// ---------------- Wt build: Wt[it][e][j] = W[it][j][e], fp16, e zero-padded to 320
__global__ void wt_build_kernel(const float* __restrict__ W, _Float16* __restrict__ Wt){
    int idx = blockIdx.x*256 + threadIdx.x;      // 2*320*128 = 81920
    if (idx >= 2*KP*SS) return;
    int j = idx & 127;
    int e = (idx >> 7) % KP;
    int it = idx / (KP*SS);
    float v = (e < EE) ? W[(size_t)it*SS*EE + j*EE + e] : 0.f;
    Wt[idx] = (_Float16)v;
}

// ---------------- pack conv weights: per it, 32 dwords:
// [0..5] h2(w0,w1) per (c,dy); [6..11] h2(w1,w2); [12..17] f32 w0; [18..23] f32 w2; [24] bias
__global__ void cwpack_kernel(const float* __restrict__ cw, const float* __restrict__ cb,
                              float* __restrict__ pwt){
    int t = threadIdx.x;
    if (t < 12){
        int it = t / 6, rem = t % 6;          // rem = c*3+dy
        const float* w = cw + it*18 + rem*3;
        float a = w[0], b = w[1], d = w[2];
        h2 p01 = { (_Float16)a, (_Float16)b };
        h2 p12 = { (_Float16)b, (_Float16)d };
        float* o = pwt + it*32;
        ((unsigned*)o)[rem]   = __builtin_bit_cast(unsigned, p01);
        ((unsigned*)o)[6+rem] = __builtin_bit_cast(unsigned, p12);
        o[12+rem] = a;
        o[18+rem] = d;
    }
    if (t < 2) pwt[t*32+24] = cb[t];
}

// ---------------- embed: gather -> sf16 + valid mask + fused seg-0 mean ------
// grid (bc, 32, 2), block 256 (4 waves, wave = 1 row); res must be zeroed
__global__ __launch_bounds__(256) void embed_kernel(
    const int* __restrict__ seq1, const int* __restrict__ seq2,
    const float* __restrict__ emb,
    _Float16* __restrict__ sf1, _Float16* __restrict__ sf2,
    float* __restrict__ v1, float* __restrict__ v2,
    float* __restrict__ res, int b0){
    __shared__ float mred[4][320];
    int bl = blockIdx.x, which = blockIdx.z;
    int w = threadIdx.x >> 6;
    int r = blockIdx.y*4 + w;
    int l = threadIdx.x & 63;
    const int* seq = which ? seq2 : seq1;
    _Float16* sfg = (which ? sf2 : sf1) + (size_t)bl*SS*KP;
    float* vd = (which ? v2 : v1) + bl*SS;
    int token = seq[(size_t)(b0+bl)*SS + r];
    if (l == 0) vd[r] = (token != 0) ? 1.f : 0.f;
    const float* er = emb + (size_t)token * EE;
    int e0 = l*8;
    float x[8];
    if (l < 37){
        float4 a = *(const float4*)(er + e0);
        float4 b = *(const float4*)(er + e0 + 4);
        x[0]=a.x; x[1]=a.y; x[2]=a.z; x[3]=a.w;
        x[4]=b.x; x[5]=b.y; x[6]=b.z; x[7]=b.w;
    } else if (l == 37){
        x[0]=er[296]; x[1]=er[297]; x[2]=er[298]; x[3]=er[299];
        x[4]=0.f; x[5]=0.f; x[6]=0.f; x[7]=0.f;
    } else {
        #pragma unroll
        for (int j = 0; j < 8; j++) x[j] = 0.f;
    }
    if (l < 40){
        half8 hv;
        #pragma unroll
        for (int j = 0; j < 8; j++) hv[j] = (_Float16)x[j];
        *(half8*)(sfg + r*KP + e0) = hv;
        #pragma unroll
        for (int j = 0; j < 8; j++) mred[w][e0 + j] = x[j];
    }
    __syncthreads();
    for (int e = threadIdx.x; e < EE; e += 256){
        float s = mred[0][e] + mred[1][e] + mred[2][e] + mred[3][e];
        atomicAdd(&res[(size_t)(b0+bl)*FCIN + which*900 + e], s * (1.f/SS));
    }
}

// ---------------- MFMA match (A-producing): stages sf16*v, self-computes norms
// block 512 (8 waves); wave = 16 rows x 128 cols. Writes Ab AND AbT.
// 1-ahead register prefetch: next chunk's global loads issued between the
// barriers so they fly during the MFMA section.
__global__ __launch_bounds__(512, 4) void cross_matchA(
    const _Float16* __restrict__ sfA, const _Float16* __restrict__ sfB,
    const float* __restrict__ vAg, const float* __restrict__ vBg,
    _Float16* __restrict__ Ab16, _Float16* __restrict__ AbT16)
{
    __shared__ _Float16 As[128][40];
    __shared__ _Float16 Bs[128][40];
    __shared__ float nAl[128], nBl[128], vAl[128], vBl[128];

    int bl = blockIdx.x;
    int tid = threadIdx.x;
    int w = tid >> 6, lane = tid & 63;
    int m = lane & 15, quad = lane >> 4;

    const _Float16* gA = sfA + (size_t)bl*SS*KP;
    const _Float16* gB = sfB + (size_t)bl*SS*KP;

    if (tid < 128){ vAl[tid] = vAg[bl*SS + tid]; }
    else if (tid < 256){ vBl[tid-128] = vBg[bl*SS + tid-128]; }

    f32x4 acc[8];
    #pragma unroll
    for (int c = 0; c < 8; c++) acc[c] = (f32x4){0.f,0.f,0.f,0.f};

    int srow = tid >> 2, skq = (tid & 3) * 8;
    int arow = w*16 + m;
    float nA = 0.f, nB = 0.f;

    half8 ha = *(const half8*)(gA + srow*KP + skq);     // chunk 0
    half8 hb = *(const half8*)(gB + srow*KP + skq);
    __syncthreads();                                    // vAl/vBl visible

    for (int kc = 0; kc < 10; kc++){
        {
            half8 sa = ha * (_Float16)vAl[srow];
            half8 sb = hb * (_Float16)vBl[srow];
            *(half8*)&As[srow][skq] = sa;
            *(half8*)&Bs[srow][skq] = sb;
            nA = norm8(sa, nA);
            nB = norm8(sb, nB);
        }
        __syncthreads();                                // stores visible; nothing in flight
        if (kc < 9){                                    // prefetch flies during MFMA
            ha = *(const half8*)(gA + srow*KP + (kc+1)*32 + skq);
            hb = *(const half8*)(gB + srow*KP + (kc+1)*32 + skq);
        }
        half8 a = *(const half8*)&As[arow][quad*8];
        #pragma unroll
        for (int c = 0; c < 8; c++){
            half8 b = *(const half8*)&Bs[c*16 + m][quad*8];
            acc[c] = __builtin_amdgcn_mfma_f32_16x16x32_f16(a, b, acc[c], 0, 0, 0);
        }
        __syncthreads();                                // reads done; drain ~finished prefetch
    }

    nA += __shfl_xor(nA, 1); nA += __shfl_xor(nA, 2);
    nB += __shfl_xor(nB, 1); nB += __shfl_xor(nB, 2);
    if ((tid & 3) == 0){ nAl[srow] = nA; nBl[srow] = nB; }
    __syncthreads();

    int ibase = w*16 + quad*4;
    _Float16* Ao = Ab16 + (size_t)bl*SS*SS;
    _Float16* AoT = AbT16 + (size_t)bl*SS*SS;
    #pragma unroll
    for (int c = 0; c < 8; c++){
        int j = c*16 + m;
        float nc = nBl[j];
        #pragma unroll
        for (int r = 0; r < 4; r++){
            int i = ibase + r;
            float d2 = nAl[i] + nc - 2.f*acc[c][r];
            _Float16 val = (_Float16)inv1p_sqrt(d2);
            Ao[i*SS + j] = val;
            AoT[j*SS + i] = val;
        }
    }
}

// ---------------- MFMA match sums + fused pool/residual (norms self-computed)
// block 512; same 1-ahead prefetch staging as cross_matchA.
__global__ __launch_bounds__(512, 4) void cross_sums_pool(
    const _Float16* __restrict__ oA, const _Float16* __restrict__ oB,
    const float* __restrict__ vAg, const float* __restrict__ vBg,
    _Float16* __restrict__ sf1, _Float16* __restrict__ sf2)
{
    __shared__ _Float16 As[128][40];
    __shared__ _Float16 Bs[128][40];
    __shared__ float nAl[128], nBl[128], vAl[128], vBl[128];
    __shared__ float colred[8][132];
    __shared__ float wr[128], wc[128];

    int bl = blockIdx.x;
    int tid = threadIdx.x;
    int w = tid >> 6, lane = tid & 63;
    int m = lane & 15, quad = lane >> 4;

    const _Float16* gA = oA + (size_t)bl*SS*KP;
    const _Float16* gB = oB + (size_t)bl*SS*KP;

    if (tid < 128){ vAl[tid] = vAg[bl*SS + tid]; }
    else if (tid < 256){ vBl[tid-128] = vBg[bl*SS + tid-128]; }

    f32x4 acc[8];
    #pragma unroll
    for (int c = 0; c < 8; c++) acc[c] = (f32x4){0.f,0.f,0.f,0.f};

    int srow = tid >> 2, skq = (tid & 3) * 8;
    int arow = w*16 + m;
    float nA = 0.f, nB = 0.f;

    half8 ha = *(const half8*)(gA + srow*KP + skq);     // chunk 0
    half8 hb = *(const half8*)(gB + srow*KP + skq);
    __syncthreads();                                    // vAl/vBl visible

    for (int kc = 0; kc < 10; kc++){
        {
            half8 sa = ha * (_Float16)vAl[srow];
            half8 sb = hb * (_Float16)vBl[srow];
            *(half8*)&As[srow][skq] = sa;
            *(half8*)&Bs[srow][skq] = sb;
            nA = norm8(sa, nA);
            nB = norm8(sb, nB);
        }
        __syncthreads();
        if (kc < 9){
            ha = *(const half8*)(gA + srow*KP + (kc+1)*32 + skq);
            hb = *(const half8*)(gB + srow*KP + (kc+1)*32 + skq);
        }
        half8 a = *(const half8*)&As[arow][quad*8];
        #pragma unroll
        for (int c = 0; c < 8; c++){
            half8 b = *(const half8*)&Bs[c*16 + m][quad*8];
            acc[c] = __builtin_amdgcn_mfma_f32_16x16x32_f16(a, b, acc[c], 0, 0, 0);
        }
        __syncthreads();
    }

    nA += __shfl_xor(nA, 1); nA += __shfl_xor(nA, 2);
    nB += __shfl_xor(nB, 1); nB += __shfl_xor(nB, 2);
    if ((tid & 3) == 0){ nAl[srow] = nA; nBl[srow] = nB; }
    __syncthreads();

    int ibase = w*16 + quad*4;
    float aval[8][4];
    #pragma unroll
    for (int c = 0; c < 8; c++){
        float nc = nBl[c*16 + m];
        #pragma unroll
        for (int r = 0; r < 4; r++){
            float d2 = nAl[ibase+r] + nc - 2.f*acc[c][r];
            aval[c][r] = inv1p_sqrt(d2);
        }
    }

    // row sums -> wr
    float rp[4];
    #pragma unroll
    for (int r = 0; r < 4; r++){
        float s = 0.f;
        #pragma unroll
        for (int c = 0; c < 8; c++) s += aval[c][r];
        rp[r] = s;
    }
    #pragma unroll
    for (int mask = 1; mask < 16; mask <<= 1)
        #pragma unroll
        for (int r = 0; r < 4; r++) rp[r] += __shfl_xor(rp[r], mask);
    if (m == 0){
        #pragma unroll
        for (int r = 0; r < 4; r++) wr[ibase + r] = rp[r];
    }
    // col sums -> wc
    float cp[8];
    #pragma unroll
    for (int c = 0; c < 8; c++){
        float s = 0.f;
        #pragma unroll
        for (int r = 0; r < 4; r++) s += aval[c][r];
        cp[c] = s;
    }
    #pragma unroll
    for (int c = 0; c < 8; c++){
        cp[c] += __shfl_xor(cp[c], 16);
        cp[c] += __shfl_xor(cp[c], 32);
    }
    if (quad == 0){
        #pragma unroll
        for (int c = 0; c < 8; c++) colred[w][c*16 + m] = cp[c];
    }
    __syncthreads();
    if (tid < 128){
        float s = 0.f;
        #pragma unroll
        for (int g = 0; g < 8; g++) s += colred[g][tid];
        wc[tid] = s;
    }
    __syncthreads();

    // ---- fused pool epilogue: 4 lanes per row (tid>>2 = row, tid&3 = sub) ----
    int prow = tid >> 2, sub = tid & 3;
    #pragma unroll
    for (int which = 0; which < 2; which++){
        const _Float16* og = which ? gB : gA;
        const float* wv = which ? wc : wr;
        _Float16* sg = (which ? sf2 : sf1) + (size_t)bl*SS*KP;
        float w0 = wv[prow];
        float wm = (prow > 0)   ? wv[prow-1] : 0.f;
        float wp = (prow < 127) ? wv[prow+1] : 0.f;
        #pragma unroll
        for (int k = 0; k < 10; k++){
            int e0 = (sub + k*4) * 8;           // < 320
            half8 o0 = *(const half8*)(og + prow*KP + e0);
            half8 om = {};
            half8 op = {};
            if (prow > 0)   om = *(const half8*)(og + (prow-1)*KP + e0);
            if (prow < 127) op = *(const half8*)(og + (prow+1)*KP + e0);
            half8 sv = *(const half8*)(sg + prow*KP + e0);
            half8 outh;
            #pragma unroll
            for (int j = 0; j < 8; j++){
                float a = (float)o0[j]*w0 + (float)om[j]*wm + (float)op[j]*wp;
                float ns = (float)sv[j] + a * (1.f/3.f);
                outh[j] = (_Float16)ns;
            }
            *(half8*)(sg + prow*KP + e0) = outh;
        }
    }
}

// ---------------- fused f = A@W (zz=0) / A^T@W (zz=1, from AbT) -> LDS -------
// -> conv3x3 + tanh -> o16 + fused column-mean (atomicAdd into res).
// grid (bc, 4 row-strips, 2), block 256 (4 waves).
// Phase 1 (loop-interchanged): hold all 12 A-fragments in regs; per col-frag
// load each Wt B-fragment ONCE and feed 3 independent MFMA chains (one per
// rowgroup) -> Wt L2 traffic /3, 3-way MFMA ILP. Bit-identical math.
// Phase 2: preloaded ch0 rows (10-deep MLP), row-pair conv, coalesced stores.
__global__ __launch_bounds__(256, 4) void f_conv_kernel(
    const _Float16* __restrict__ Ab, const _Float16* __restrict__ AbT,
    const _Float16* __restrict__ Wt,
    const _Float16* __restrict__ sf1, const _Float16* __restrict__ sf2,
    const float* __restrict__ pw,
    _Float16* __restrict__ o16_1, _Float16* __restrict__ o16_2,
    float* __restrict__ res, int b0, int seg)
{
    __shared__ _Float16 ftile[48][328];          // +8 pad: de-conflict phase-1 writes

    int bl = blockIdx.x, rs = blockIdx.y, zz = blockIdx.z;
    int R0 = rs*32 - 8;
    int tid = threadIdx.x, w = tid >> 6, lane = tid & 63;
    int m = lane & 15, quad = lane >> 4;

    // conv weights (uniform loads)
    const unsigned* pu = (const unsigned*)pw;
    h2 w01[2][3], w12[2][3];
    float w0f[2][3], w2f[2][3];
    #pragma unroll
    for (int c = 0; c < 2; c++)
        #pragma unroll
        for (int dy = 0; dy < 3; dy++){
            int rem = c*3 + dy;
            w01[c][dy] = __builtin_bit_cast(h2, pu[rem]);
            w12[c][dy] = __builtin_bit_cast(h2, pu[6 + rem]);
            w0f[c][dy] = pw[12 + rem];
            w2f[c][dy] = pw[18 + rem];
        }
    float bias = pw[24];

    // ---- phase 1: f rows [R0, R0+48) x cols 0..303 via MFMA ----
    const _Float16* gA = (zz ? AbT : Ab) + (size_t)bl*SS*SS;
    half8 a[3][4];
    #pragma unroll
    for (int rg = 0; rg < 3; rg++){
        int gar = R0 + rg*16 + m;                      // A row for this lane
        int gac = gar < 0 ? 0 : (gar > SS-1 ? SS-1 : gar);   // clamp (OOB rows zeroed below)
        #pragma unroll
        for (int kc = 0; kc < 4; kc++)
            a[rg][kc] = *(const half8*)(gA + gac*SS + kc*32 + quad*8);
    }
    #pragma unroll
    for (int ci = 0; ci < 5; ci++){
        int c = w + ci*4;                              // wave-strided col frags
        if (c < 19){
            int e = c*16 + m;                          // 0..303
            half8 b[4];
            #pragma unroll
            for (int kc = 0; kc < 4; kc++)
                b[kc] = *(const half8*)(Wt + (size_t)e*SS + kc*32 + quad*8);
            f32x4 acc[3];
            #pragma unroll
            for (int rg = 0; rg < 3; rg++) acc[rg] = (f32x4){0.f,0.f,0.f,0.f};
            #pragma unroll
            for (int kc = 0; kc < 4; kc++)
                #pragma unroll
                for (int rg = 0; rg < 3; rg++)
                    acc[rg] = __builtin_amdgcn_mfma_f32_16x16x32_f16(a[rg][kc], b[kc], acc[rg], 0, 0, 0);
            #pragma unroll
            for (int rg = 0; rg < 3; rg++){
                #pragma unroll
                for (int r = 0; r < 4; r++){
                    int lr = rg*16 + quad*4 + r;
                    int gf = R0 + lr;
                    bool ok = (gf >= 0) && (gf < SS) && (e < EE);
                    ftile[lr][e] = ok ? (_Float16)acc[rg][r] : (_Float16)0.f;
                }
            }
        }
    }
    // zero-fill cols 304..319 (uniform padding for conv)
    for (int idx = tid; idx < 48*16; idx += 256)
        ftile[idx >> 4][304 + (idx & 15)] = (_Float16)0.f;
    __syncthreads();

    // ---- phase 2: conv(3x3, ch0=sf regs, ch1=f LDS) + tanh -> o16 ----
    const _Float16* cs = (zz ? sf2 : sf1) + (size_t)bl*SS*KP;
    _Float16* od = (zz ? o16_2 : o16_1) + (size_t)bl*SS*KP;
    int l = lane, e0 = l*8;
    bool lok = (l < 40);
    int eok = lok ? e0 : 0;                       // dead lanes load col 0 (masked)
    float msum[8];
    #pragma unroll
    for (int j = 0; j < 8; j++) msum[j] = 0.f;

    // preload all 10 ch0 rows (branchless clamped loads, masked to zero)
    half8 s[10];
    int rbase = rs*32 + w*8 - 1;
    #pragma unroll
    for (int q = 0; q < 10; q++){
        int gr = rbase + q;
        int gc = gr < 0 ? 0 : (gr > SS-1 ? SS-1 : gr);
        half8 t = *(const half8*)(cs + gc*KP + eok);
        bool ok = (gr >= 0) && (gr < SS) && lok;
        s[q] = ok ? t : (half8){};
    }

    #pragma unroll
    for (int p = 0; p < 4; p++){
        int roA = rs*32 + w*8 + 2*p;            // output rows roA, roA+1
        int lrA = w*8 + 2*p + 8;                // ftile local row of roA
        float accA[8], accB[8];
        #pragma unroll
        for (int j = 0; j < 8; j++){ accA[j] = bias; accB[j] = bias; }

        #pragma unroll
        for (int c = 0; c < 2; c++){
            #pragma unroll
            for (int q = 0; q < 4; q++){        // input row = roA - 1 + q
                half8 hv;
                if (c == 0){
                    hv = s[2*p + q];
                } else {
                    hv = *(const half8*)&ftile[lrA - 1 + q][eok];
                    if (!lok) hv = (half8){};
                }
                h2 d0 = __builtin_shufflevector(hv, hv, 0, 1);
                h2 d1 = __builtin_shufflevector(hv, hv, 2, 3);
                h2 d2 = __builtin_shufflevector(hv, hv, 4, 5);
                h2 d3 = __builtin_shufflevector(hv, hv, 6, 7);
                int dmi = __shfl_up(__builtin_bit_cast(int, d3), 1);
                int dpi = __shfl_down(__builtin_bit_cast(int, d0), 1);
                h2 dmh = __builtin_bit_cast(h2, dmi);
                h2 dph = __builtin_bit_cast(h2, dpi);
                float xm = (l == 0) ? 0.f : (float)dmh[1];
                float xp = (float)dph[0];
                if (q <= 2)
                    conv_row(accA, w01[c][q], w12[c][q], w0f[c][q], w2f[c][q],
                             d0, d1, d2, d3, xm, xp);
                if (q >= 1)
                    conv_row(accB, w01[c][q-1], w12[c][q-1], w0f[c][q-1], w2f[c][q-1],
                             d0, d1, d2, d3, xm, xp);
            }
        }

        half8 outA, outB;
        #pragma unroll
        for (int j = 0; j < 8; j++){
            bool ev = (e0 + j < EE);
            float tA = ev ? fast_tanh(accA[j]) : 0.f;
            float tB = ev ? fast_tanh(accB[j]) : 0.f;
            outA[j] = (_Float16)tA;
            outB[j] = (_Float16)tB;
            msum[j] += tA + tB;
        }
        if (lok){
            *(half8*)(od + roA*KP + e0) = outA;
            *(half8*)(od + (roA+1)*KP + e0) = outB;
        }
    }

    // ---- fused column-mean: LDS partial over 4 waves, atomicAdd into res ----
    __syncthreads();                             // all ftile reads done
    float* mred = (float*)&ftile[0][0];          // alias: [4][320] floats
    if (lok){
        #pragma unroll
        for (int j = 0; j < 8; j++) mred[w*320 + e0 + j] = msum[j];
    }
    __syncthreads();
    for (int e = tid; e < EE; e += 256){
        float s2 = mred[e] + mred[320+e] + mred[640+e] + mred[960+e];
        atomicAdd(&res[(size_t)(b0+bl)*FCIN + zz*900 + seg*300 + e], s2 * (1.f/SS));
    }
}

// ---------------- fc1: K-split x6, atomic accumulate into h ------------------
// grid (8,5,6), block 256; h must be zeroed before launch
#define CKK 12
__global__ __launch_bounds__(256) void fc1_kernel(const float* __restrict__ res,
                                                  const float* __restrict__ fw,
                                                  float* __restrict__ h){
    __shared__ float Xt[CKK][68];
    __shared__ float Wts[CKK][68];
    int bt = blockIdx.x, jt = blockIdx.y, kz = blockIdx.z;
    int tid = threadIdx.x, tx = tid & 15, ty = tid >> 4;
    int b0l = bt*64, j0 = jt*64, kbase = kz*300;
    float acc[4][4] = {};
    for (int k0 = 0; k0 < 300; k0 += CKK){
        #pragma unroll
        for (int u = 0; u < 3; u++){
            int idx = tid + u*256;
            int a = idx / CKK, k = idx - a*CKK;
            Xt[k][a] = res[(size_t)(b0l+a)*FCIN + kbase + k0 + k];
            int gj = j0 + a;
            Wts[k][a] = (gj < HH) ? fw[(size_t)gj*FCIN + kbase + k0 + k] : 0.f;
        }
        __syncthreads();
        #pragma unroll
        for (int k = 0; k < CKK; k++){
            float xv[4], wv[4];
            #pragma unroll
            for (int r = 0; r < 4; r++) xv[r] = Xt[k][ty*4+r];
            #pragma unroll
            for (int c = 0; c < 4; c++) wv[c] = Wts[k][tx*4+c];
            #pragma unroll
            for (int r = 0; r < 4; r++)
                #pragma unroll
                for (int c = 0; c < 4; c++)
                    acc[r][c] = fmaf(xv[r], wv[c], acc[r][c]);
        }
        __syncthreads();
    }
    #pragma unroll
    for (int r = 0; r < 4; r++){
        int gb = b0l + ty*4 + r;
        #pragma unroll
        for (int c = 0; c < 4; c++){
            int gj = j0 + tx*4 + c;
            if (gj < HH) atomicAdd(&h[(size_t)gb*HH + gj], acc[r][c]);
        }
    }
}

// ---------------- layernorm + relu + fc2 + softmax (+fc1 bias) ---------------
__global__ void head_kernel(const float* __restrict__ h, const float* __restrict__ fb,
                            const float* __restrict__ g,
                            const float* __restrict__ be, const float* __restrict__ f2w,
                            const float* __restrict__ f2b, float* __restrict__ out){
    int b = blockIdx.x, tid = threadIdx.x;
    __shared__ float arr[HH];
    __shared__ float s_s[4], s_q[4], r0[4], r1[4];
    float x0 = (tid < HH) ? h[(size_t)b*HH + tid] + fb[tid] : 0.f;
    float x1 = (tid + 256 < HH) ? h[(size_t)b*HH + tid + 256] + fb[tid+256] : 0.f;
    float s = x0 + x1, sq = x0*x0 + x1*x1;
    #pragma unroll
    for (int o = 32; o > 0; o >>= 1){ s += __shfl_down(s, o); sq += __shfl_down(sq, o); }
    int wv = tid >> 6, ln = tid & 63;
    if (ln == 0){ s_s[wv] = s; s_q[wv] = sq; }
    __syncthreads();
    s  = s_s[0] + s_s[1] + s_s[2] + s_s[3];
    sq = s_q[0] + s_q[1] + s_q[2] + s_q[3];
    float mean = s / HH;
    float var = sq / HH - mean*mean;
    float inv = rsqrtf(var + 1e-5f);
    if (tid < HH)       arr[tid]     = fmaxf((x0 - mean)*inv*g[tid]     + be[tid],     0.f);
    if (tid + 256 < HH) arr[tid+256] = fmaxf((x1 - mean)*inv*g[tid+256] + be[tid+256], 0.f);
    __syncthreads();
    float p0 = 0.f, p1 = 0.f;
    for (int j = tid; j < HH; j += 256){ float hv = arr[j]; p0 += hv*f2w[j]; p1 += hv*f2w[HH+j]; }
    #pragma unroll
    for (int o = 32; o > 0; o >>= 1){ p0 += __shfl_down(p0, o); p1 += __shfl_down(p1, o); }
    if (ln == 0){ r0[wv] = p0; r1[wv] = p1; }
    __syncthreads();
    if (tid == 0){
        float o0 = r0[0]+r0[1]+r0[2]+r0[3] + f2b[0];
        float o1 = r1[0]+r1[1]+r1[2]+r1[3] + f2b[1];
        out[b*2+0] = o0; out[b*2+1] = o1;
        float m = fmaxf(o0, o1);
        float e0 = __expf(o0 - m), e1 = __expf(o1 - m);
        float den = e0 + e1;
        out[BB*2 + b*2+0] = e0/den;
        out[BB*2 + b*2+1] = e1/den;
    }
}

extern "C" void kernel_launch(void* const* d_in, const int* in_sizes, int n_in,
                              void* d_out, int out_size, void* d_ws, size_t ws_size,
                              hipStream_t stream){
    const int*   seq1   = (const int*)d_in[0];
    const int*   seq2   = (const int*)d_in[1];
    const float* emb    = (const float*)d_in[2];
    const float* W      = (const float*)d_in[3];
    const float* conv_w = (const float*)d_in[4];
    const float* conv_b = (const float*)d_in[5];
    const float* fc1_w  = (const float*)d_in[6];
    const float* fc1_b  = (const float*)d_in[7];
    const float* ln_g   = (const float*)d_in[8];
    const float* ln_b   = (const float*)d_in[9];
    const float* fc2_w  = (const float*)d_in[10];
    const float* fc2_b  = (const float*)d_in[11];
    float* out = (float*)d_out;

    float* ws = (float*)d_ws;
    size_t fixedf = (size_t)BB*FCIN + (size_t)BB*HH + (size_t)KP*SS + 64;
    // per-batch floats: sf16 + o16 (each 2*SS*KP halves) + Ab + AbT + 2 vecs
    size_t perb = (size_t)2*SS*KP + (size_t)(SS*SS) + 2*SS;
    size_t avail = ws_size / 4;
    long long bcl = (long long)((avail > fixedf ? avail - fixedf : 0) / perb);
    int BC = (int)(bcl < 1 ? 1 : (bcl > BB ? BB : bcl));

    float* res = ws;
    float* hb  = res + (size_t)BB*FCIN;
    _Float16* Wt = (_Float16*)(hb + (size_t)BB*HH);
    float* pwt = (float*)(Wt + (size_t)2*KP*SS);
    _Float16* sf1 = (_Float16*)(pwt + 64);
    _Float16* sf2 = sf1 + (size_t)BC*SS*KP;
    _Float16* o16_1 = sf2 + (size_t)BC*SS*KP;
    _Float16* o16_2 = o16_1 + (size_t)BC*SS*KP;
    _Float16* Ab  = o16_2 + (size_t)BC*SS*KP;
    _Float16* AbT = Ab + (size_t)BC*SS*SS;
    float* v1  = (float*)(AbT + (size_t)BC*SS*SS);
    float* v2  = v1 + (size_t)BC*SS;

    wt_build_kernel<<<(2*KP*SS + 255)/256, 256, 0, stream>>>(W, Wt);
    cwpack_kernel<<<1, 64, 0, stream>>>(conv_w, conv_b, pwt);
    hipMemsetAsync(hb, 0, (size_t)BB*HH*sizeof(float), stream);
    hipMemsetAsync(res, 0, (size_t)BB*FCIN*sizeof(float), stream);

    for (int b0 = 0; b0 < BB; b0 += BC){
        int bc = (BB - b0 < BC) ? (BB - b0) : BC;
        embed_kernel<<<dim3(bc, 32, 2), 256, 0, stream>>>(seq1, seq2, emb, sf1, sf2,
                                                          v1, v2, res, b0);
        for (int it = 0; it < LLI; it++){
            cross_matchA<<<bc, 512, 0, stream>>>(sf1, sf2, v1, v2, Ab, AbT);
            f_conv_kernel<<<dim3(bc, 4, 2), 256, 0, stream>>>(Ab, AbT, Wt + (size_t)it*KP*SS,
                                                              sf1, sf2, pwt + it*32,
                                                              o16_1, o16_2, res, b0, it+1);
            cross_sums_pool<<<bc, 512, 0, stream>>>(o16_1, o16_2, v1, v2, sf1, sf2);
        }
    }
    fc1_kernel<<<dim3(8, 5, 6), 256, 0, stream>>>(res, fc1_w, hb);
    head_kernel<<<BB, 256, 0, stream>>>(hb, fc1_b, ln_g, ln_b, fc2_w, fc2_b, out);
}